// Round 9
// baseline (1020.902 us; speedup 1.0000x reference)
//
#include <hip/hip_runtime.h>

typedef unsigned short u16;
typedef unsigned int   u32;
typedef float  f32x4  __attribute__((ext_vector_type(4)));
typedef __bf16 bf16x8 __attribute__((ext_vector_type(8)));
typedef u32    u32x4  __attribute__((ext_vector_type(4)));
typedef u32    u32x2  __attribute__((ext_vector_type(2)));

#define Bb  8
#define Nn  1024
#define Dd  256
#define Hh  8
#define HDd 32
#define CAP 96

__device__ __forceinline__ float bf2f(u16 s){
  u32 u = ((u32)s) << 16; float f; __builtin_memcpy(&f, &u, 4); return f;
}
__device__ __forceinline__ u16 f2bf(float f){
  u32 u; __builtin_memcpy(&u, &f, 4);
  u = (u + 0x7fffu + ((u >> 16) & 1u)) >> 16;
  return (u16)u;
}
__device__ __forceinline__ f32x4 mfma16(bf16x8 a, bf16x8 b, f32x4 c){
  return __builtin_amdgcn_mfma_f32_16x16x32_bf16(a, b, c, 0, 0, 0);
}
__device__ __forceinline__ bf16x8 ld_bf8(const u16* p){
  u32x4 u = *(const u32x4*)p; bf16x8 r; __builtin_memcpy(&r, &u, 16); return r;
}

// ---------------- f32 -> bf16 convert ----------------
__global__ void f32_to_bf16(const float* __restrict__ src, u16* __restrict__ dst, int n){
  int i = (blockIdx.x * 256 + threadIdx.x) * 4;
  if (i < n){
    f32x4 v = *(const f32x4*)(src + i);
    u32x2 p;
    p[0] = (u32)f2bf(v[0]) | ((u32)f2bf(v[1]) << 16);
    p[1] = (u32)f2bf(v[2]) | ((u32)f2bf(v[3]) << 16);
    *(u32x2*)(dst + i) = p;
  }
}

// ---------------- 4-weight convert (Wq,Wk,Wv,Wo -> contiguous bf16) ----------------
__global__ void conv_w4(const float* __restrict__ wq, const float* __restrict__ wk,
                        const float* __restrict__ wv, const float* __restrict__ wo,
                        u16* __restrict__ dst){
  int g = blockIdx.x * 256 + threadIdx.x;      // 0..196607
  int sec = g / 49152, off = (g - sec * 49152) * 4;
  const float* src = (sec == 0 ? wq : sec == 1 ? wk : sec == 2 ? wv : wo);
  f32x4 v = *(const f32x4*)(src + off);
  u32x2 p;
  p[0] = (u32)f2bf(v[0]) | ((u32)f2bf(v[1]) << 16);
  p[1] = (u32)f2bf(v[2]) | ((u32)f2bf(v[3]) << 16);
  *(u32x2*)(dst + sec * 196608 + off) = p;
}

// ---------------- bias concat ----------------
__global__ void bias_concat(const float* __restrict__ bq, const float* __restrict__ bk,
                            const float* __restrict__ bv, float* __restrict__ bqkv){
  int t = threadIdx.x;   // 256
  for (int l = 0; l < 3; ++l){
    bqkv[l*768 +       t] = bq[l*256 + t];
    bqkv[l*768 + 256 + t] = bk[l*256 + t];
    bqkv[l*768 + 512 + t] = bv[l*256 + t];
  }
}

// ---------------- adj -> bitmask ----------------
__global__ void adj_to_bits(const float* __restrict__ adj, u32* __restrict__ bits){
  int w = blockIdx.x * 256 + threadIdx.x;        // word over [1024][32]
  const float* p = adj + (long)w * 32;
  u32 m = 0;
  #pragma unroll
  for (int t = 0; t < 32; t += 4){
    f32x4 v = *(const f32x4*)(p + t);
    if (v[0] != 0.f) m |= 1u << (t+0);
    if (v[1] != 0.f) m |= 1u << (t+1);
    if (v[2] != 0.f) m |= 1u << (t+2);
    if (v[3] != 0.f) m |= 1u << (t+3);
  }
  bits[w] = m;
}

// ---------------- neighbor list build (CSR, capacity CAP) ----------------
__global__ __launch_bounds__(256) void nbr_build(const u32* __restrict__ bits,
                                                 u16* __restrict__ idx, int* __restrict__ cnt){
  int i = blockIdx.x * 256 + threadIdx.x;        // grid 4
  int c = 0;
  for (int w = 0; w < 32; ++w){
    u32 wd = bits[i*32 + w];
    while (wd){
      int bi = __ffs(wd) - 1; wd &= wd - 1;
      if (c < CAP) idx[(long)i*CAP + c] = (u16)(w*32 + bi);
      ++c;
    }
  }
  cnt[i] = (c < CAP) ? c : CAP;
}

// ---------------- MFMA GEMM: C[m][n] = sum_k A[m][k]*Bt[n][k] (+bias) ----------------
// VALIDATED (R4-R8); sbc = per-blockz bias stride (0 for legacy call sites).
template<bool HBC, bool HBR, bool OF, bool OB>
__global__ __launch_bounds__(256,2) void gemm_bt(
    const u16* __restrict__ A, int lda, long sA,
    const u16* __restrict__ Bt, int ldb, long sB,
    float* __restrict__ Cf, u16* __restrict__ Cb, int ldc, long sC,
    int K, const float* __restrict__ bc, long sbc, const float* __restrict__ br)
{
  __shared__ u16 As[128][40];
  __shared__ u16 Bs[128][40];
  const int bz = blockIdx.z;
  const u16* Ap = A + (long)bz * sA;
  const u16* Bp = Bt + (long)bz * sB;
  const long co = (long)bz * sC;
  const int m0 = blockIdx.y * 128, n0 = blockIdx.x * 128;
  const int tid = threadIdx.x, wave = tid >> 6, lane = tid & 63;
  const int arow = lane & 15, agrp = lane >> 4;
  const int wr = (wave >> 1) * 64, wc = (wave & 1) * 64;
  const int srow = tid >> 1, sch = (tid & 1) * 16;
  const u16* ga = Ap + (long)(m0 + srow) * lda + sch;
  const u16* gb = Bp + (long)(n0 + srow) * ldb + sch;
  f32x4 acc[4][4] = {};
  for (int kb = 0; kb < K; kb += 32){
    u32x4 a0 = *(const u32x4*)ga; u32x4 a1 = *(const u32x4*)(ga + 8);
    u32x4 b0 = *(const u32x4*)gb; u32x4 b1 = *(const u32x4*)(gb + 8);
    __syncthreads();
    *(u32x4*)&As[srow][sch] = a0; *(u32x4*)&As[srow][sch + 8] = a1;
    *(u32x4*)&Bs[srow][sch] = b0; *(u32x4*)&Bs[srow][sch + 8] = b1;
    __syncthreads();
    ga += 32; gb += 32;
    bf16x8 af[4], bv[4];
    #pragma unroll
    for (int f = 0; f < 4; ++f){
      af[f] = ld_bf8(&As[wr + f*16 + arow][agrp*8]);
      bv[f] = ld_bf8(&Bs[wc + f*16 + arow][agrp*8]);
    }
    #pragma unroll
    for (int fm = 0; fm < 4; ++fm)
      #pragma unroll
      for (int fn = 0; fn < 4; ++fn)
        acc[fm][fn] = mfma16(af[fm], bv[fn], acc[fm][fn]);
  }
  #pragma unroll
  for (int fm = 0; fm < 4; ++fm){
    #pragma unroll
    for (int fn = 0; fn < 4; ++fn){
      int j = n0 + wc + fn*16 + arow;
      float badd = 0.f;
      if (HBC) badd = bc[(long)bz*sbc + j];
      #pragma unroll
      for (int r = 0; r < 4; ++r){
        int i = m0 + wr + fm*16 + agrp*4 + r;
        float v = acc[fm][fn][r] + badd;
        if (HBR) v += br[i];
        long idx = co + (long)i * ldc + j;
        if (OF) Cf[idx] = v;
        if (OB) Cb[idx] = f2bf(v);
      }
    }
  }
}

// ---------------- sparse attention v2: LDS-staged softmax, XCD-batch affinity ----------------
// 1D grid 2048: b = bid&7 (-> XCD b under round-robin), i0 = (bid>>3)*4.
__global__ __launch_bounds__(256,4) void attn_sparse(
    const u16* __restrict__ qkv,          // [B*N][768] bf16: q|k|v
    u16* __restrict__ ob,                 // [B*N][256] bf16
    const u16* __restrict__ idxg, const int* __restrict__ cntg,
    float* __restrict__ amv)              // [B*N][CAP] f32 (slots < cnt valid)
{
  __shared__ float qs[4][256];            // q rows, pre-scaled f32
  __shared__ float E[4][CAP][8];          // raw scores -> unnormalized exp
  __shared__ float invl[4][8];            // per-(row,head) 1/sum
  __shared__ u16   idxl[4][CAP];
  __shared__ int   cntl[4];
  const int bid = blockIdx.x;
  const int b = bid & 7, i0 = (bid >> 3) * 4;
  const int tid = threadIdx.x, w = tid >> 6, lane = tid & 63;
  const float SCALE = 0.17677669529663687f;   // 1/sqrt(32)

  { int e = tid * 4, rr = e >> 8, c = e & 255;
    u32x2 uv = *(const u32x2*)(qkv + ((long)(b*Nn + i0 + rr)) * 768 + c);
    qs[rr][c+0] = SCALE * bf2f((u16)(uv[0] & 0xffff));
    qs[rr][c+1] = SCALE * bf2f((u16)(uv[0] >> 16));
    qs[rr][c+2] = SCALE * bf2f((u16)(uv[1] & 0xffff));
    qs[rr][c+3] = SCALE * bf2f((u16)(uv[1] >> 16)); }
  for (int s = tid; s < 4*CAP; s += 256){
    int rr = s / CAP, ss = s - rr*CAP;
    idxl[rr][ss] = idxg[(long)(i0 + rr)*CAP + ss];
  }
  if (tid < 4) cntl[tid] = cntg[i0 + tid];
  __syncthreads();

  const int i = i0 + w;
  const int cnt = cntl[w];

  // ---- Phase A: raw scores -> E[w][s][0..7] ----
  for (int s = lane; s < cnt; s += 64){
    int j = idxl[w][s];
    const u16* kp = qkv + ((long)(b*Nn + j)) * 768 + 256;
    const f32x4* q4 = (const f32x4*)&qs[w][0];
    float sc[8] = {};
    #pragma unroll
    for (int c = 0; c < 32; ++c){
      bf16x8 kv = ld_bf8(kp + c*8);
      f32x4 q0 = q4[c*2], q1 = q4[c*2 + 1];
      sc[c>>2] += q0[0]*(float)kv[0] + q0[1]*(float)kv[1] + q0[2]*(float)kv[2] + q0[3]*(float)kv[3]
                + q1[0]*(float)kv[4] + q1[1]*(float)kv[5] + q1[2]*(float)kv[6] + q1[3]*(float)kv[7];
    }
    *(f32x4*)&E[w][s][0] = *(f32x4*)&sc[0];
    *(f32x4*)&E[w][s][4] = *(f32x4*)&sc[4];
  }
  __syncthreads();

  // ---- Phase B: per-head max/sum; lane = h*8+k owns slots s==k (mod 8) ----
  { const int h = lane >> 3, k = lane & 7;
    float m = -3.0e38f;
    for (int s = k; s < cnt; s += 8) m = fmaxf(m, E[w][s][h]);
    m = fmaxf(m, __shfl_xor(m, 1, 64));
    m = fmaxf(m, __shfl_xor(m, 2, 64));
    m = fmaxf(m, __shfl_xor(m, 4, 64));
    float l = 0.f;
    for (int s = k; s < cnt; s += 8){
      float e = __expf(E[w][s][h] - m);
      E[w][s][h] = e; l += e;
    }
    l += __shfl_xor(l, 1, 64);
    l += __shfl_xor(l, 2, 64);
    l += __shfl_xor(l, 4, 64);
    if (k == 0) invl[w][h] = 1.f / l;
  }
  __syncthreads();

  // ---- Phase C: amv[s] = 0.125 * sum_h E[s][h]*invl[h] ----
  { f32x4 i0v = *(f32x4*)&invl[w][0], i1v = *(f32x4*)&invl[w][4];
    for (int s = lane; s < cnt; s += 64){
      f32x4 e0 = *(f32x4*)&E[w][s][0], e1 = *(f32x4*)&E[w][s][4];
      float a = e0[0]*i0v[0] + e0[1]*i0v[1] + e0[2]*i0v[2] + e0[3]*i0v[3]
              + e1[0]*i1v[0] + e1[1]*i1v[1] + e1[2]*i1v[2] + e1[3]*i1v[3];
      amv[((long)(b*Nn + i))*CAP + s] = a * 0.125f;
    }
  }

  // ---- Phase D: PV; lane owns 4 output dims of head h = lane>>3 ----
  { const int d0 = lane * 4, h = lane >> 3;
    f32x4 acc = {0.f, 0.f, 0.f, 0.f};
    for (int s = 0; s < cnt; ++s){
      int j = idxl[w][s];
      float ev = E[w][s][h];
      u32x2 vv = *(const u32x2*)(qkv + ((long)(b*Nn + j)) * 768 + 512 + d0);
      acc[0] += ev * bf2f((u16)(vv[0] & 0xffff));
      acc[1] += ev * bf2f((u16)(vv[0] >> 16));
      acc[2] += ev * bf2f((u16)(vv[1] & 0xffff));
      acc[3] += ev * bf2f((u16)(vv[1] >> 16));
    }
    float nl = invl[w][h];
    u32x2 pb;
    pb[0] = (u32)f2bf(acc[0]*nl) | ((u32)f2bf(acc[1]*nl) << 16);
    pb[1] = (u32)f2bf(acc[2]*nl) | ((u32)f2bf(acc[3]*nl) << 16);
    *(u32x2*)(ob + ((long)(b*Nn + i)) * 256 + d0) = pb;
  }
}

// ---------------- sparse chain 1 ----------------
__global__ __launch_bounds__(256) void sp_gemm1(
    const float* __restrict__ amv1, const float* __restrict__ amv0,
    const u16* __restrict__ idxg, const int* __restrict__ cntg,
    u16* __restrict__ P1)                 // [B*N][1024] bf16
{
  __shared__ float accum[1024];
  __shared__ u16 idxl[CAP];
  __shared__ float v1[CAP];
  const int b = blockIdx.y, i = blockIdx.x, tid = threadIdx.x;
  { f32x4 z = {0.f,0.f,0.f,0.f}; *(f32x4*)&accum[tid*4] = z; }
  const int cnt = cntg[i];
  if (tid < CAP){
    idxl[tid] = idxg[(long)i*CAP + tid];
    v1[tid]   = amv1[((long)(b*Nn + i))*CAP + tid];
  }
  __syncthreads();
  const int npairs = cnt * 64;
  for (int p = tid; p < npairs; p += 256){
    int s = p >> 6, t = p & 63;
    int j = idxl[s];
    int cj = cntg[j];
    float vs = v1[s];
    if (t < cj){
      int col = idxg[(long)j*CAP + t];
      atomicAdd(&accum[col], vs * amv0[((long)(b*Nn + j))*CAP + t]);
    }
    if (cj > 64 && t + 64 < cj){
      int col = idxg[(long)j*CAP + t + 64];
      atomicAdd(&accum[col], vs * amv0[((long)(b*Nn + j))*CAP + t + 64]);
    }
  }
  __syncthreads();
  int c0 = tid * 4;
  u32x2 pb;
  pb[0] = (u32)f2bf(accum[c0])   | ((u32)f2bf(accum[c0+1]) << 16);
  pb[1] = (u32)f2bf(accum[c0+2]) | ((u32)f2bf(accum[c0+3]) << 16);
  *(u32x2*)(P1 + ((long)(b*Nn + i))*1024 + c0) = pb;
}

// ---------------- sparse chain 2 ----------------
__global__ __launch_bounds__(256) void sp_gemm2(
    const float* __restrict__ amv2, const u16* __restrict__ P1,
    const u16* __restrict__ idxg, const int* __restrict__ cntg,
    float* __restrict__ out)              // [B*N][1024] f32 (d_out atten)
{
  __shared__ u16 idxl[CAP];
  __shared__ float v2[CAP];
  const int b = blockIdx.y, i = blockIdx.x, tid = threadIdx.x;
  const int cnt = cntg[i];
  if (tid < CAP){
    idxl[tid] = idxg[(long)i*CAP + tid];
    v2[tid]   = amv2[((long)(b*Nn + i))*CAP + tid];
  }
  __syncthreads();
  f32x4 acc = {0.f, 0.f, 0.f, 0.f};
  const int c0 = tid * 4;
  for (int s = 0; s < cnt; ++s){
    int j = idxl[s];
    float ev = v2[s];
    u32x2 vv = *(const u32x2*)(P1 + ((long)(b*Nn + j))*1024 + c0);
    acc[0] += ev * bf2f((u16)(vv[0] & 0xffff));
    acc[1] += ev * bf2f((u16)(vv[0] >> 16));
    acc[2] += ev * bf2f((u16)(vv[1] & 0xffff));
    acc[3] += ev * bf2f((u16)(vv[1] >> 16));
  }
  *(f32x4*)(out + ((long)(b*Nn + i))*1024 + c0) = acc;
}

// ---------------- residual + layernorm ----------------
__global__ __launch_bounds__(256) void ln_kernel(
    const float* __restrict__ hin, const float* __restrict__ y,
    float* __restrict__ hout, u16* __restrict__ hb, float* __restrict__ outf,
    const float* __restrict__ g, const float* __restrict__ be)
{
  int row  = blockIdx.x * 4 + (threadIdx.x >> 6);
  int lane = threadIdx.x & 63;
  f32x4 v = *(const f32x4*)(hin + (long)row*Dd + lane*4)
          + *(const f32x4*)(y   + (long)row*Dd + lane*4);
  float s = v[0] + v[1] + v[2] + v[3];
  #pragma unroll
  for (int off = 32; off; off >>= 1) s += __shfl_xor(s, off, 64);
  float mu = s * (1.f/256.f);
  f32x4 d = v - mu;
  float q2 = d[0]*d[0] + d[1]*d[1] + d[2]*d[2] + d[3]*d[3];
  #pragma unroll
  for (int off = 32; off; off >>= 1) q2 += __shfl_xor(q2, off, 64);
  float rs = rsqrtf(q2 * (1.f/256.f) + 1e-5f);
  f32x4 ov;
  #pragma unroll
  for (int p = 0; p < 4; ++p)
    ov[p] = d[p] * rs * g[lane*4 + p] + be[lane*4 + p];
  *(f32x4*)(hout + (long)row*Dd + lane*4) = ov;
  if (hb){
    u32x2 pb;
    pb[0] = (u32)f2bf(ov[0]) | ((u32)f2bf(ov[1]) << 16);
    pb[1] = (u32)f2bf(ov[2]) | ((u32)f2bf(ov[3]) << 16);
    *(u32x2*)(hb + (long)row*Dd + lane*4) = pb;
  }
  if (outf)
    *(f32x4*)(outf + (long)row*Dd + lane*4) = ov;
}

extern "C" void kernel_launch(void* const* d_in, const int* in_sizes, int n_in,
                              void* d_out, int out_size, void* d_ws, size_t ws_size,
                              hipStream_t stream)
{
  (void)in_sizes; (void)n_in; (void)out_size; (void)ws_size;
  const float* x   = (const float*)d_in[0];
  const float* adj = (const float*)d_in[1];
  const float* W0  = (const float*)d_in[2];
  const float* Wq  = (const float*)d_in[3];
  const float* bq  = (const float*)d_in[4];
  const float* Wk  = (const float*)d_in[5];
  const float* bk  = (const float*)d_in[6];
  const float* Wv  = (const float*)d_in[7];
  const float* bv  = (const float*)d_in[8];
  const float* Wo  = (const float*)d_in[9];
  const float* bo  = (const float*)d_in[10];
  const float* gm  = (const float*)d_in[11];
  const float* bt  = (const float*)d_in[12];
  float* outf  = (float*)d_out;                 // f32 h region [8,1024,256]
  float* outat = outf + (long)Bb * Nn * Dd;     // f32 atten region [8,1024,1024]

  // ---- workspace (~67MB < proven 92MB) ----
  char* w = (char*)d_ws;
  u16* W0b  = (u16*)w; w += 131072;
  u16* Wqb  = (u16*)w; w += 393216;             // Wq|Wk|Wv|Wo contiguous (conv_w4)
  u16* Wkb  = (u16*)w; w += 393216;
  u16* Wvb  = (u16*)w; w += 393216;
  u16* Wob  = (u16*)w; w += 393216;
  float* bqkv = (float*)w; w += 9216;           // [3][768]
  u32* bitsg = (u32*)w; w += 131072;
  u16* idxg  = (u16*)w; w += 1024*CAP*2;        // 192KB
  int* cntg  = (int*)w; w += 4096;
  u16* xb  = (u16*)w; w += 4194304;
  u16* hb  = (u16*)w; w += 4194304;
  u16* qkv = (u16*)w; w += (long)Bb*Nn*768*2;   // 12MB
  u16* ob  = (u16*)w; w += 4194304;
  float* hbuf = (float*)w; w += 8388608;
  float* ybuf = (float*)w; w += 8388608;
  float* amv0 = (float*)w; w += (long)Bb*Nn*CAP*4;  // 3MB each
  float* amv1 = (float*)w; w += (long)Bb*Nn*CAP*4;
  float* amv2 = (float*)w; w += (long)Bb*Nn*CAP*4;
  u16* P1   = (u16*)w; w += 16777216;           // [8][1024][1024] bf16
  float* amvl[3] = {amv0, amv1, amv2};

  dim3 blk(256);
  f32_to_bf16<<<2048, blk, 0, stream>>>(x,  xb,  2097152);
  f32_to_bf16<<<64,   blk, 0, stream>>>(W0, W0b, 65536);
  conv_w4<<<768, blk, 0, stream>>>(Wq, Wk, Wv, Wo, Wqb);
  bias_concat<<<1, blk, 0, stream>>>(bq, bk, bv, bqkv);
  adj_to_bits<<<128, blk, 0, stream>>>(adj, bitsg);
  nbr_build<<<4, blk, 0, stream>>>(bitsg, idxg, cntg);

  // input projection: h = x @ W0^T  (f32 + bf16)
  gemm_bt<false,false,true,true><<<dim3(2,64,1), blk, 0, stream>>>(
      xb, 256, 0, W0b, 256, 0, hbuf, hb, 256, 0, 256, nullptr, 0, nullptr);

  for (int l = 0; l < 3; ++l){
    // fused q|k|v projection: grid z selects weight section and C column offset
    gemm_bt<true,false,false,true><<<dim3(2,64,3), blk, 0, stream>>>(
        hb, 256, 0, Wqb + (long)l*65536, 256, 196608,
        nullptr, qkv, 768, 256, 256, bqkv + l*768, 256, nullptr);
    // sparse attention (1D grid: batch = bid&7 for XCD-L2 affinity)
    attn_sparse<<<dim3(2048), blk, 0, stream>>>(qkv, ob, idxg, cntg, amvl[l]);
    // y = o @ Wo^T + bo (f32)
    gemm_bt<true,false,true,false><<<dim3(2,64,1), blk, 0, stream>>>(
        ob, 256, 0, Wob + (long)l*65536, 256, 0, ybuf, nullptr, 256, 0, 256,
        bo + l*256, 0, nullptr);
    // h = LN(h + y)
    ln_kernel<<<dim3(2048), blk, 0, stream>>>(
        hbuf, ybuf, hbuf, (l < 2 ? hb : nullptr), (l < 2 ? nullptr : outf),
        gm + l*256, bt + l*256);
    // sparse chain
    if (l == 1)
      sp_gemm1<<<dim3(1024,8), blk, 0, stream>>>(amv1, amv0, idxg, cntg, P1);
    if (l == 2)
      sp_gemm2<<<dim3(1024,8), blk, 0, stream>>>(amv2, P1, idxg, cntg, outat);
  }
}

// Round 10
// 353.172 us; speedup vs baseline: 2.8907x; 2.8907x over previous
//
#include <hip/hip_runtime.h>

typedef unsigned short u16;
typedef unsigned int   u32;
typedef float  f32x4  __attribute__((ext_vector_type(4)));
typedef __bf16 bf16x8 __attribute__((ext_vector_type(8)));
typedef u32    u32x4  __attribute__((ext_vector_type(4)));
typedef u32    u32x2  __attribute__((ext_vector_type(2)));

#define Bb  8
#define Nn  1024
#define Dd  256
#define Hh  8
#define HDd 32
#define CAP 96

__device__ __forceinline__ float bf2f(u16 s){
  u32 u = ((u32)s) << 16; float f; __builtin_memcpy(&f, &u, 4); return f;
}
__device__ __forceinline__ u16 f2bf(float f){
  u32 u; __builtin_memcpy(&u, &f, 4);
  u = (u + 0x7fffu + ((u >> 16) & 1u)) >> 16;
  return (u16)u;
}
__device__ __forceinline__ f32x4 mfma16(bf16x8 a, bf16x8 b, f32x4 c){
  return __builtin_amdgcn_mfma_f32_16x16x32_bf16(a, b, c, 0, 0, 0);
}
__device__ __forceinline__ bf16x8 ld_bf8(const u16* p){
  u32x4 u = *(const u32x4*)p; bf16x8 r; __builtin_memcpy(&r, &u, 16); return r;
}

// ---------------- f32 -> bf16 convert ----------------
__global__ void f32_to_bf16(const float* __restrict__ src, u16* __restrict__ dst, int n){
  int i = (blockIdx.x * 256 + threadIdx.x) * 4;
  if (i < n){
    f32x4 v = *(const f32x4*)(src + i);
    u32x2 p;
    p[0] = (u32)f2bf(v[0]) | ((u32)f2bf(v[1]) << 16);
    p[1] = (u32)f2bf(v[2]) | ((u32)f2bf(v[3]) << 16);
    *(u32x2*)(dst + i) = p;
  }
}

// ---------------- 4-weight convert (Wq,Wk,Wv,Wo -> contiguous bf16) ----------------
__global__ void conv_w4(const float* __restrict__ wq, const float* __restrict__ wk,
                        const float* __restrict__ wv, const float* __restrict__ wo,
                        u16* __restrict__ dst){
  int g = blockIdx.x * 256 + threadIdx.x;      // 0..196607
  int sec = g / 49152, off = (g - sec * 49152) * 4;
  const float* src = (sec == 0 ? wq : sec == 1 ? wk : sec == 2 ? wv : wo);
  f32x4 v = *(const f32x4*)(src + off);
  u32x2 p;
  p[0] = (u32)f2bf(v[0]) | ((u32)f2bf(v[1]) << 16);
  p[1] = (u32)f2bf(v[2]) | ((u32)f2bf(v[3]) << 16);
  *(u32x2*)(dst + sec * 196608 + off) = p;
}

// ---------------- bias concat ----------------
__global__ void bias_concat(const float* __restrict__ bq, const float* __restrict__ bk,
                            const float* __restrict__ bv, float* __restrict__ bqkv){
  int t = threadIdx.x;   // 256
  for (int l = 0; l < 3; ++l){
    bqkv[l*768 +       t] = bq[l*256 + t];
    bqkv[l*768 + 256 + t] = bk[l*256 + t];
    bqkv[l*768 + 512 + t] = bv[l*256 + t];
  }
}

// ---------------- adj -> bitmask ----------------
__global__ void adj_to_bits(const float* __restrict__ adj, u32* __restrict__ bits){
  int w = blockIdx.x * 256 + threadIdx.x;        // word over [1024][32]
  const float* p = adj + (long)w * 32;
  u32 m = 0;
  #pragma unroll
  for (int t = 0; t < 32; t += 4){
    f32x4 v = *(const f32x4*)(p + t);
    if (v[0] != 0.f) m |= 1u << (t+0);
    if (v[1] != 0.f) m |= 1u << (t+1);
    if (v[2] != 0.f) m |= 1u << (t+2);
    if (v[3] != 0.f) m |= 1u << (t+3);
  }
  bits[w] = m;
}

// ---------------- neighbor list build (CSR, capacity CAP) ----------------
__global__ __launch_bounds__(256) void nbr_build(const u32* __restrict__ bits,
                                                 u16* __restrict__ idx, int* __restrict__ cnt){
  int i = blockIdx.x * 256 + threadIdx.x;        // grid 4
  int c = 0;
  for (int w = 0; w < 32; ++w){
    u32 wd = bits[i*32 + w];
    while (wd){
      int bi = __ffs(wd) - 1; wd &= wd - 1;
      if (c < CAP) idx[(long)i*CAP + c] = (u16)(w*32 + bi);
      ++c;
    }
  }
  cnt[i] = (c < CAP) ? c : CAP;
}

// ---------------- MFMA GEMM: C[m][n] = sum_k A[m][k]*Bt[n][k] (+bias) ----------------
// VALIDATED (R4-R8); sbc = per-blockz bias stride (0 for legacy call sites).
template<bool HBC, bool HBR, bool OF, bool OB>
__global__ __launch_bounds__(256,2) void gemm_bt(
    const u16* __restrict__ A, int lda, long sA,
    const u16* __restrict__ Bt, int ldb, long sB,
    float* __restrict__ Cf, u16* __restrict__ Cb, int ldc, long sC,
    int K, const float* __restrict__ bc, long sbc, const float* __restrict__ br)
{
  __shared__ u16 As[128][40];
  __shared__ u16 Bs[128][40];
  const int bz = blockIdx.z;
  const u16* Ap = A + (long)bz * sA;
  const u16* Bp = Bt + (long)bz * sB;
  const long co = (long)bz * sC;
  const int m0 = blockIdx.y * 128, n0 = blockIdx.x * 128;
  const int tid = threadIdx.x, wave = tid >> 6, lane = tid & 63;
  const int arow = lane & 15, agrp = lane >> 4;
  const int wr = (wave >> 1) * 64, wc = (wave & 1) * 64;
  const int srow = tid >> 1, sch = (tid & 1) * 16;
  const u16* ga = Ap + (long)(m0 + srow) * lda + sch;
  const u16* gb = Bp + (long)(n0 + srow) * ldb + sch;
  f32x4 acc[4][4] = {};
  for (int kb = 0; kb < K; kb += 32){
    u32x4 a0 = *(const u32x4*)ga; u32x4 a1 = *(const u32x4*)(ga + 8);
    u32x4 b0 = *(const u32x4*)gb; u32x4 b1 = *(const u32x4*)(gb + 8);
    __syncthreads();
    *(u32x4*)&As[srow][sch] = a0; *(u32x4*)&As[srow][sch + 8] = a1;
    *(u32x4*)&Bs[srow][sch] = b0; *(u32x4*)&Bs[srow][sch + 8] = b1;
    __syncthreads();
    ga += 32; gb += 32;
    bf16x8 af[4], bv[4];
    #pragma unroll
    for (int f = 0; f < 4; ++f){
      af[f] = ld_bf8(&As[wr + f*16 + arow][agrp*8]);
      bv[f] = ld_bf8(&Bs[wc + f*16 + arow][agrp*8]);
    }
    #pragma unroll
    for (int fm = 0; fm < 4; ++fm)
      #pragma unroll
      for (int fn = 0; fn < 4; ++fn)
        acc[fm][fn] = mfma16(af[fm], bv[fn], acc[fm][fn]);
  }
  #pragma unroll
  for (int fm = 0; fm < 4; ++fm){
    #pragma unroll
    for (int fn = 0; fn < 4; ++fn){
      int j = n0 + wc + fn*16 + arow;
      float badd = 0.f;
      if (HBC) badd = bc[(long)bz*sbc + j];
      #pragma unroll
      for (int r = 0; r < 4; ++r){
        int i = m0 + wr + fm*16 + agrp*4 + r;
        float v = acc[fm][fn][r] + badd;
        if (HBR) v += br[i];
        long idx = co + (long)i * ldc + j;
        if (OF) Cf[idx] = v;
        if (OB) Cb[idx] = f2bf(v);
      }
    }
  }
}

// ---------------- sparse attention v3: LDS softmax, no forced occupancy, half-split ----------------
// grid (256, 8): i0 = blockIdx.x*4, b = blockIdx.y  (R8 mapping: 34MB fetch, no thrash)
__global__ __launch_bounds__(256) void attn_sparse(
    const u16* __restrict__ qkv,          // [B*N][768] bf16: q|k|v
    u16* __restrict__ ob,                 // [B*N][256] bf16
    const u16* __restrict__ idxg, const int* __restrict__ cntg,
    float* __restrict__ amv)              // [B*N][CAP] f32 (slots < cnt valid)
{
  __shared__ float qs[4][256];            // q rows, pre-scaled f32
  __shared__ float E[4][CAP][8];          // raw scores -> unnormalized exp
  __shared__ float invl[4][8];            // per-(row,head) 1/sum
  __shared__ u16   idxl[4][CAP];
  __shared__ int   cntl[4];
  const int b = blockIdx.y, i0 = blockIdx.x * 4;
  const int tid = threadIdx.x, w = tid >> 6, lane = tid & 63;
  const float SCALE = 0.17677669529663687f;   // 1/sqrt(32)

  { int e = tid * 4, rr = e >> 8, c = e & 255;
    u32x2 uv = *(const u32x2*)(qkv + ((long)(b*Nn + i0 + rr)) * 768 + c);
    qs[rr][c+0] = SCALE * bf2f((u16)(uv[0] & 0xffff));
    qs[rr][c+1] = SCALE * bf2f((u16)(uv[0] >> 16));
    qs[rr][c+2] = SCALE * bf2f((u16)(uv[1] & 0xffff));
    qs[rr][c+3] = SCALE * bf2f((u16)(uv[1] >> 16)); }
  for (int s = tid; s < 4*CAP; s += 256){
    int rr = s / CAP, ss = s - rr*CAP;
    idxl[rr][ss] = idxg[(long)(i0 + rr)*CAP + ss];
  }
  if (tid < 4) cntl[tid] = cntg[i0 + tid];
  __syncthreads();

  const int i = i0 + w;
  const int cnt = cntl[w];

  // ---- Phase A: scores. Lane pair (sl, sl+32): half=0 -> heads 0-3, half=1 -> heads 4-7 ----
  { const int half = lane >> 5, sl = lane & 31;
    const f32x4* q4 = (const f32x4*)&qs[w][half * 128];
    for (int s = sl; s < cnt; s += 32){
      int j = idxl[w][s];
      const u16* kp = qkv + ((long)(b*Nn + j)) * 768 + 256 + half * 128;
      float sc[4] = {};
      #pragma unroll
      for (int c = 0; c < 16; ++c){
        bf16x8 kv = ld_bf8(kp + c*8);
        f32x4 q0 = q4[c*2], q1 = q4[c*2 + 1];
        sc[c>>2] += q0[0]*(float)kv[0] + q0[1]*(float)kv[1] + q0[2]*(float)kv[2] + q0[3]*(float)kv[3]
                  + q1[0]*(float)kv[4] + q1[1]*(float)kv[5] + q1[2]*(float)kv[6] + q1[3]*(float)kv[7];
      }
      *(f32x4*)&E[w][s][half*4] = *(f32x4*)&sc[0];
    }
  }
  __syncthreads();

  // ---- Phase B: per-head max/sum; lane = h*8+k owns slots s==k (mod 8) ----
  { const int h = lane >> 3, k = lane & 7;
    float m = -3.0e38f;
    for (int s = k; s < cnt; s += 8) m = fmaxf(m, E[w][s][h]);
    m = fmaxf(m, __shfl_xor(m, 1, 64));
    m = fmaxf(m, __shfl_xor(m, 2, 64));
    m = fmaxf(m, __shfl_xor(m, 4, 64));
    float l = 0.f;
    for (int s = k; s < cnt; s += 8){
      float e = __expf(E[w][s][h] - m);
      E[w][s][h] = e; l += e;
    }
    l += __shfl_xor(l, 1, 64);
    l += __shfl_xor(l, 2, 64);
    l += __shfl_xor(l, 4, 64);
    if (k == 0) invl[w][h] = 1.f / l;
  }
  __syncthreads();

  // ---- Phase C: amv[s] = 0.125 * sum_h E[s][h]*invl[h] ----
  { f32x4 i0v = *(f32x4*)&invl[w][0], i1v = *(f32x4*)&invl[w][4];
    for (int s = lane; s < cnt; s += 64){
      f32x4 e0 = *(f32x4*)&E[w][s][0], e1 = *(f32x4*)&E[w][s][4];
      float a = e0[0]*i0v[0] + e0[1]*i0v[1] + e0[2]*i0v[2] + e0[3]*i0v[3]
              + e1[0]*i1v[0] + e1[1]*i1v[1] + e1[2]*i1v[2] + e1[3]*i1v[3];
      amv[((long)(b*Nn + i))*CAP + s] = a * 0.125f;
    }
  }

  // ---- Phase D: PV; lane owns 4 output dims of head h = lane>>3 ----
  { const int d0 = lane * 4, h = lane >> 3;
    f32x4 acc = {0.f, 0.f, 0.f, 0.f};
    for (int s = 0; s < cnt; ++s){
      int j = idxl[w][s];
      float ev = E[w][s][h];
      u32x2 vv = *(const u32x2*)(qkv + ((long)(b*Nn + j)) * 768 + 512 + d0);
      acc[0] += ev * bf2f((u16)(vv[0] & 0xffff));
      acc[1] += ev * bf2f((u16)(vv[0] >> 16));
      acc[2] += ev * bf2f((u16)(vv[1] & 0xffff));
      acc[3] += ev * bf2f((u16)(vv[1] >> 16));
    }
    float nl = invl[w][h];
    u32x2 pb;
    pb[0] = (u32)f2bf(acc[0]*nl) | ((u32)f2bf(acc[1]*nl) << 16);
    pb[1] = (u32)f2bf(acc[2]*nl) | ((u32)f2bf(acc[3]*nl) << 16);
    *(u32x2*)(ob + ((long)(b*Nn + i)) * 256 + d0) = pb;
  }
}

// ---------------- sparse chain 1 ----------------
__global__ __launch_bounds__(256) void sp_gemm1(
    const float* __restrict__ amv1, const float* __restrict__ amv0,
    const u16* __restrict__ idxg, const int* __restrict__ cntg,
    u16* __restrict__ P1)                 // [B*N][1024] bf16
{
  __shared__ float accum[1024];
  __shared__ u16 idxl[CAP];
  __shared__ float v1[CAP];
  const int b = blockIdx.y, i = blockIdx.x, tid = threadIdx.x;
  { f32x4 z = {0.f,0.f,0.f,0.f}; *(f32x4*)&accum[tid*4] = z; }
  const int cnt = cntg[i];
  if (tid < CAP){
    idxl[tid] = idxg[(long)i*CAP + tid];
    v1[tid]   = amv1[((long)(b*Nn + i))*CAP + tid];
  }
  __syncthreads();
  const int npairs = cnt * 64;
  for (int p = tid; p < npairs; p += 256){
    int s = p >> 6, t = p & 63;
    int j = idxl[s];
    int cj = cntg[j];
    float vs = v1[s];
    if (t < cj){
      int col = idxg[(long)j*CAP + t];
      atomicAdd(&accum[col], vs * amv0[((long)(b*Nn + j))*CAP + t]);
    }
    if (cj > 64 && t + 64 < cj){
      int col = idxg[(long)j*CAP + t + 64];
      atomicAdd(&accum[col], vs * amv0[((long)(b*Nn + j))*CAP + t + 64]);
    }
  }
  __syncthreads();
  int c0 = tid * 4;
  u32x2 pb;
  pb[0] = (u32)f2bf(accum[c0])   | ((u32)f2bf(accum[c0+1]) << 16);
  pb[1] = (u32)f2bf(accum[c0+2]) | ((u32)f2bf(accum[c0+3]) << 16);
  *(u32x2*)(P1 + ((long)(b*Nn + i))*1024 + c0) = pb;
}

// ---------------- sparse chain 2 ----------------
__global__ __launch_bounds__(256) void sp_gemm2(
    const float* __restrict__ amv2, const u16* __restrict__ P1,
    const u16* __restrict__ idxg, const int* __restrict__ cntg,
    float* __restrict__ out)              // [B*N][1024] f32 (d_out atten)
{
  __shared__ u16 idxl[CAP];
  __shared__ float v2[CAP];
  const int b = blockIdx.y, i = blockIdx.x, tid = threadIdx.x;
  const int cnt = cntg[i];
  if (tid < CAP){
    idxl[tid] = idxg[(long)i*CAP + tid];
    v2[tid]   = amv2[((long)(b*Nn + i))*CAP + tid];
  }
  __syncthreads();
  f32x4 acc = {0.f, 0.f, 0.f, 0.f};
  const int c0 = tid * 4;
  for (int s = 0; s < cnt; ++s){
    int j = idxl[s];
    float ev = v2[s];
    u32x2 vv = *(const u32x2*)(P1 + ((long)(b*Nn + j))*1024 + c0);
    acc[0] += ev * bf2f((u16)(vv[0] & 0xffff));
    acc[1] += ev * bf2f((u16)(vv[0] >> 16));
    acc[2] += ev * bf2f((u16)(vv[1] & 0xffff));
    acc[3] += ev * bf2f((u16)(vv[1] >> 16));
  }
  *(f32x4*)(out + ((long)(b*Nn + i))*1024 + c0) = acc;
}

// ---------------- residual + layernorm ----------------
__global__ __launch_bounds__(256) void ln_kernel(
    const float* __restrict__ hin, const float* __restrict__ y,
    float* __restrict__ hout, u16* __restrict__ hb, float* __restrict__ outf,
    const float* __restrict__ g, const float* __restrict__ be)
{
  int row  = blockIdx.x * 4 + (threadIdx.x >> 6);
  int lane = threadIdx.x & 63;
  f32x4 v = *(const f32x4*)(hin + (long)row*Dd + lane*4)
          + *(const f32x4*)(y   + (long)row*Dd + lane*4);
  float s = v[0] + v[1] + v[2] + v[3];
  #pragma unroll
  for (int off = 32; off; off >>= 1) s += __shfl_xor(s, off, 64);
  float mu = s * (1.f/256.f);
  f32x4 d = v - mu;
  float q2 = d[0]*d[0] + d[1]*d[1] + d[2]*d[2] + d[3]*d[3];
  #pragma unroll
  for (int off = 32; off; off >>= 1) q2 += __shfl_xor(q2, off, 64);
  float rs = rsqrtf(q2 * (1.f/256.f) + 1e-5f);
  f32x4 ov;
  #pragma unroll
  for (int p = 0; p < 4; ++p)
    ov[p] = d[p] * rs * g[lane*4 + p] + be[lane*4 + p];
  *(f32x4*)(hout + (long)row*Dd + lane*4) = ov;
  if (hb){
    u32x2 pb;
    pb[0] = (u32)f2bf(ov[0]) | ((u32)f2bf(ov[1]) << 16);
    pb[1] = (u32)f2bf(ov[2]) | ((u32)f2bf(ov[3]) << 16);
    *(u32x2*)(hb + (long)row*Dd + lane*4) = pb;
  }
  if (outf)
    *(f32x4*)(outf + (long)row*Dd + lane*4) = ov;
}

extern "C" void kernel_launch(void* const* d_in, const int* in_sizes, int n_in,
                              void* d_out, int out_size, void* d_ws, size_t ws_size,
                              hipStream_t stream)
{
  (void)in_sizes; (void)n_in; (void)out_size; (void)ws_size;
  const float* x   = (const float*)d_in[0];
  const float* adj = (const float*)d_in[1];
  const float* W0  = (const float*)d_in[2];
  const float* Wq  = (const float*)d_in[3];
  const float* bq  = (const float*)d_in[4];
  const float* Wk  = (const float*)d_in[5];
  const float* bk  = (const float*)d_in[6];
  const float* Wv  = (const float*)d_in[7];
  const float* bv  = (const float*)d_in[8];
  const float* Wo  = (const float*)d_in[9];
  const float* bo  = (const float*)d_in[10];
  const float* gm  = (const float*)d_in[11];
  const float* bt  = (const float*)d_in[12];
  float* outf  = (float*)d_out;                 // f32 h region [8,1024,256]
  float* outat = outf + (long)Bb * Nn * Dd;     // f32 atten region [8,1024,1024]

  // ---- workspace (~67MB < proven 92MB) ----
  char* w = (char*)d_ws;
  u16* W0b  = (u16*)w; w += 131072;
  u16* Wqb  = (u16*)w; w += 393216;             // Wq|Wk|Wv|Wo contiguous (conv_w4)
  u16* Wkb  = (u16*)w; w += 393216;
  u16* Wvb  = (u16*)w; w += 393216;
  u16* Wob  = (u16*)w; w += 393216;
  float* bqkv = (float*)w; w += 9216;           // [3][768]
  u32* bitsg = (u32*)w; w += 131072;
  u16* idxg  = (u16*)w; w += 1024*CAP*2;        // 192KB
  int* cntg  = (int*)w; w += 4096;
  u16* xb  = (u16*)w; w += 4194304;
  u16* hb  = (u16*)w; w += 4194304;
  u16* qkv = (u16*)w; w += (long)Bb*Nn*768*2;   // 12MB
  u16* ob  = (u16*)w; w += 4194304;
  float* hbuf = (float*)w; w += 8388608;
  float* ybuf = (float*)w; w += 8388608;
  float* amv0 = (float*)w; w += (long)Bb*Nn*CAP*4;  // 3MB each
  float* amv1 = (float*)w; w += (long)Bb*Nn*CAP*4;
  float* amv2 = (float*)w; w += (long)Bb*Nn*CAP*4;
  u16* P1   = (u16*)w; w += 16777216;           // [8][1024][1024] bf16
  float* amvl[3] = {amv0, amv1, amv2};

  dim3 blk(256);
  f32_to_bf16<<<2048, blk, 0, stream>>>(x,  xb,  2097152);
  f32_to_bf16<<<64,   blk, 0, stream>>>(W0, W0b, 65536);
  conv_w4<<<768, blk, 0, stream>>>(Wq, Wk, Wv, Wo, Wqb);
  bias_concat<<<1, blk, 0, stream>>>(bq, bk, bv, bqkv);
  adj_to_bits<<<128, blk, 0, stream>>>(adj, bitsg);
  nbr_build<<<4, blk, 0, stream>>>(bitsg, idxg, cntg);

  // input projection: h = x @ W0^T  (f32 + bf16)
  gemm_bt<false,false,true,true><<<dim3(2,64,1), blk, 0, stream>>>(
      xb, 256, 0, W0b, 256, 0, hbuf, hb, 256, 0, 256, nullptr, 0, nullptr);

  for (int l = 0; l < 3; ++l){
    // fused q|k|v projection: grid z selects weight section and C column offset
    gemm_bt<true,false,false,true><<<dim3(2,64,3), blk, 0, stream>>>(
        hb, 256, 0, Wqb + (long)l*65536, 256, 196608,
        nullptr, qkv, 768, 256, 256, bqkv + l*768, 256, nullptr);
    // sparse attention (grid (256,8): consecutive blocks share batch)
    attn_sparse<<<dim3(256,8), blk, 0, stream>>>(qkv, ob, idxg, cntg, amvl[l]);
    // y = o @ Wo^T + bo (f32)
    gemm_bt<true,false,true,false><<<dim3(2,64,1), blk, 0, stream>>>(
        ob, 256, 0, Wob + (long)l*65536, 256, 0, ybuf, nullptr, 256, 0, 256,
        bo + l*256, 0, nullptr);
    // h = LN(h + y)
    ln_kernel<<<dim3(2048), blk, 0, stream>>>(
        hbuf, ybuf, hbuf, (l < 2 ? hb : nullptr), (l < 2 ? nullptr : outf),
        gm + l*256, bt + l*256);
    // sparse chain
    if (l == 1)
      sp_gemm1<<<dim3(1024,8), blk, 0, stream>>>(amv1, amv0, idxg, cntg, P1);
    if (l == 2)
      sp_gemm2<<<dim3(1024,8), blk, 0, stream>>>(amv2, P1, idxg, cntg, outat);
  }
}

// Round 11
// 319.173 us; speedup vs baseline: 3.1986x; 1.1065x over previous
//
#include <hip/hip_runtime.h>

typedef unsigned short u16;
typedef unsigned int   u32;
typedef float  f32x4  __attribute__((ext_vector_type(4)));
typedef __bf16 bf16x8 __attribute__((ext_vector_type(8)));
typedef u32    u32x4  __attribute__((ext_vector_type(4)));
typedef u32    u32x2  __attribute__((ext_vector_type(2)));

#define Bb  8
#define Nn  1024
#define Dd  256
#define Hh  8
#define HDd 32
#define CAP 96

__device__ __forceinline__ float bf2f(u16 s){
  u32 u = ((u32)s) << 16; float f; __builtin_memcpy(&f, &u, 4); return f;
}
__device__ __forceinline__ u16 f2bf(float f){
  u32 u; __builtin_memcpy(&u, &f, 4);
  u = (u + 0x7fffu + ((u >> 16) & 1u)) >> 16;
  return (u16)u;
}
__device__ __forceinline__ f32x4 mfma16(bf16x8 a, bf16x8 b, f32x4 c){
  return __builtin_amdgcn_mfma_f32_16x16x32_bf16(a, b, c, 0, 0, 0);
}
__device__ __forceinline__ bf16x8 ld_bf8(const u16* p){
  u32x4 u = *(const u32x4*)p; bf16x8 r; __builtin_memcpy(&r, &u, 16); return r;
}

// ---------------- f32 -> bf16 convert ----------------
__global__ void f32_to_bf16(const float* __restrict__ src, u16* __restrict__ dst, int n){
  int i = (blockIdx.x * 256 + threadIdx.x) * 4;
  if (i < n){
    f32x4 v = *(const f32x4*)(src + i);
    u32x2 p;
    p[0] = (u32)f2bf(v[0]) | ((u32)f2bf(v[1]) << 16);
    p[1] = (u32)f2bf(v[2]) | ((u32)f2bf(v[3]) << 16);
    *(u32x2*)(dst + i) = p;
  }
}

// ---------------- 4-weight convert (Wq,Wk,Wv,Wo -> contiguous bf16) ----------------
__global__ void conv_w4(const float* __restrict__ wq, const float* __restrict__ wk,
                        const float* __restrict__ wv, const float* __restrict__ wo,
                        u16* __restrict__ dst){
  int g = blockIdx.x * 256 + threadIdx.x;      // 0..196607
  int sec = g / 49152, off = (g - sec * 49152) * 4;
  const float* src = (sec == 0 ? wq : sec == 1 ? wk : sec == 2 ? wv : wo);
  f32x4 v = *(const f32x4*)(src + off);
  u32x2 p;
  p[0] = (u32)f2bf(v[0]) | ((u32)f2bf(v[1]) << 16);
  p[1] = (u32)f2bf(v[2]) | ((u32)f2bf(v[3]) << 16);
  *(u32x2*)(dst + sec * 196608 + off) = p;
}

// ---------------- bias concat ----------------
__global__ void bias_concat(const float* __restrict__ bq, const float* __restrict__ bk,
                            const float* __restrict__ bv, float* __restrict__ bqkv){
  int t = threadIdx.x;   // 256
  for (int l = 0; l < 3; ++l){
    bqkv[l*768 +       t] = bq[l*256 + t];
    bqkv[l*768 + 256 + t] = bk[l*256 + t];
    bqkv[l*768 + 512 + t] = bv[l*256 + t];
  }
}

// ---------------- adj -> bitmask ----------------
__global__ void adj_to_bits(const float* __restrict__ adj, u32* __restrict__ bits){
  int w = blockIdx.x * 256 + threadIdx.x;        // word over [1024][32]
  const float* p = adj + (long)w * 32;
  u32 m = 0;
  #pragma unroll
  for (int t = 0; t < 32; t += 4){
    f32x4 v = *(const f32x4*)(p + t);
    if (v[0] != 0.f) m |= 1u << (t+0);
    if (v[1] != 0.f) m |= 1u << (t+1);
    if (v[2] != 0.f) m |= 1u << (t+2);
    if (v[3] != 0.f) m |= 1u << (t+3);
  }
  bits[w] = m;
}

// ---------------- neighbor list build (CSR, capacity CAP) ----------------
__global__ __launch_bounds__(256) void nbr_build(const u32* __restrict__ bits,
                                                 u16* __restrict__ idx, int* __restrict__ cnt){
  int i = blockIdx.x * 256 + threadIdx.x;        // grid 4
  int c = 0;
  for (int w = 0; w < 32; ++w){
    u32 wd = bits[i*32 + w];
    while (wd){
      int bi = __ffs(wd) - 1; wd &= wd - 1;
      if (c < CAP) idx[(long)i*CAP + c] = (u16)(w*32 + bi);
      ++c;
    }
  }
  cnt[i] = (c < CAP) ? c : CAP;
}

// ---------------- MFMA GEMM: C[m][n] = sum_k A[m][k]*Bt[n][k] (+bias) ----------------
// VALIDATED (R4-R10); sbc = per-blockz bias stride (0 for legacy call sites).
template<bool HBC, bool HBR, bool OF, bool OB>
__global__ __launch_bounds__(256,2) void gemm_bt(
    const u16* __restrict__ A, int lda, long sA,
    const u16* __restrict__ Bt, int ldb, long sB,
    float* __restrict__ Cf, u16* __restrict__ Cb, int ldc, long sC,
    int K, const float* __restrict__ bc, long sbc, const float* __restrict__ br)
{
  __shared__ u16 As[128][40];
  __shared__ u16 Bs[128][40];
  const int bz = blockIdx.z;
  const u16* Ap = A + (long)bz * sA;
  const u16* Bp = Bt + (long)bz * sB;
  const long co = (long)bz * sC;
  const int m0 = blockIdx.y * 128, n0 = blockIdx.x * 128;
  const int tid = threadIdx.x, wave = tid >> 6, lane = tid & 63;
  const int arow = lane & 15, agrp = lane >> 4;
  const int wr = (wave >> 1) * 64, wc = (wave & 1) * 64;
  const int srow = tid >> 1, sch = (tid & 1) * 16;
  const u16* ga = Ap + (long)(m0 + srow) * lda + sch;
  const u16* gb = Bp + (long)(n0 + srow) * ldb + sch;
  f32x4 acc[4][4] = {};
  for (int kb = 0; kb < K; kb += 32){
    u32x4 a0 = *(const u32x4*)ga; u32x4 a1 = *(const u32x4*)(ga + 8);
    u32x4 b0 = *(const u32x4*)gb; u32x4 b1 = *(const u32x4*)(gb + 8);
    __syncthreads();
    *(u32x4*)&As[srow][sch] = a0; *(u32x4*)&As[srow][sch + 8] = a1;
    *(u32x4*)&Bs[srow][sch] = b0; *(u32x4*)&Bs[srow][sch + 8] = b1;
    __syncthreads();
    ga += 32; gb += 32;
    bf16x8 af[4], bv[4];
    #pragma unroll
    for (int f = 0; f < 4; ++f){
      af[f] = ld_bf8(&As[wr + f*16 + arow][agrp*8]);
      bv[f] = ld_bf8(&Bs[wc + f*16 + arow][agrp*8]);
    }
    #pragma unroll
    for (int fm = 0; fm < 4; ++fm)
      #pragma unroll
      for (int fn = 0; fn < 4; ++fn)
        acc[fm][fn] = mfma16(af[fm], bv[fn], acc[fm][fn]);
  }
  #pragma unroll
  for (int fm = 0; fm < 4; ++fm){
    #pragma unroll
    for (int fn = 0; fn < 4; ++fn){
      int j = n0 + wc + fn*16 + arow;
      float badd = 0.f;
      if (HBC) badd = bc[(long)bz*sbc + j];
      #pragma unroll
      for (int r = 0; r < 4; ++r){
        int i = m0 + wr + fm*16 + agrp*4 + r;
        float v = acc[fm][fn][r] + badd;
        if (HBR) v += br[i];
        long idx = co + (long)i * ldc + j;
        if (OF) Cf[idx] = v;
        if (OB) Cb[idx] = f2bf(v);
      }
    }
  }
}

// ---------------- sparse attention v4: coalesced Phase A (8-lane group reduce) ----------------
// grid (256, 8): i0 = blockIdx.x*4, b = blockIdx.y
__global__ __launch_bounds__(256) void attn_sparse(
    const u16* __restrict__ qkv,          // [B*N][768] bf16: q|k|v
    u16* __restrict__ ob,                 // [B*N][256] bf16
    const u16* __restrict__ idxg, const int* __restrict__ cntg,
    float* __restrict__ amv)              // [B*N][CAP] f32 (slots < cnt valid)
{
  __shared__ float qs[4][256];            // q rows, pre-scaled f32
  __shared__ float E[4][CAP][8];          // raw scores -> unnormalized exp
  __shared__ float invl[4][8];            // per-(row,head) 1/sum
  __shared__ u16   idxl[4][CAP];
  __shared__ int   cntl[4];
  const int b = blockIdx.y, i0 = blockIdx.x * 4;
  const int tid = threadIdx.x, w = tid >> 6, lane = tid & 63;
  const float SCALE = 0.17677669529663687f;   // 1/sqrt(32)

  { int e = tid * 4, rr = e >> 8, c = e & 255;
    u32x2 uv = *(const u32x2*)(qkv + ((long)(b*Nn + i0 + rr)) * 768 + c);
    qs[rr][c+0] = SCALE * bf2f((u16)(uv[0] & 0xffff));
    qs[rr][c+1] = SCALE * bf2f((u16)(uv[0] >> 16));
    qs[rr][c+2] = SCALE * bf2f((u16)(uv[1] & 0xffff));
    qs[rr][c+3] = SCALE * bf2f((u16)(uv[1] >> 16)); }
  for (int s = tid; s < 4*CAP; s += 256){
    int rr = s / CAP, ss = s - rr*CAP;
    idxl[rr][ss] = idxg[(long)(i0 + rr)*CAP + ss];
  }
  if (tid < 4) cntl[tid] = cntg[i0 + tid];
  __syncthreads();

  const int i = i0 + w;
  const int cnt = cntl[w];

  // ---- Phase A: wave iterates neighbors; lane owns 4 dims; coalesced 512B row reads ----
  { const f32x4 qreg = *(const f32x4*)&qs[w][lane*4];
    const int h = lane >> 3;
    int s = 0;
    for (; s + 2 <= cnt; s += 2){
      int ja = idxl[w][s], jb = idxl[w][s+1];
      u32x2 ka = *(const u32x2*)(qkv + ((long)(b*Nn + ja))*768 + 256 + lane*4);
      u32x2 kb = *(const u32x2*)(qkv + ((long)(b*Nn + jb))*768 + 256 + lane*4);
      float pa = qreg[0]*bf2f((u16)(ka[0]&0xffff)) + qreg[1]*bf2f((u16)(ka[0]>>16))
               + qreg[2]*bf2f((u16)(ka[1]&0xffff)) + qreg[3]*bf2f((u16)(ka[1]>>16));
      float pb = qreg[0]*bf2f((u16)(kb[0]&0xffff)) + qreg[1]*bf2f((u16)(kb[0]>>16))
               + qreg[2]*bf2f((u16)(kb[1]&0xffff)) + qreg[3]*bf2f((u16)(kb[1]>>16));
      pa += __shfl_xor(pa, 1, 64); pa += __shfl_xor(pa, 2, 64); pa += __shfl_xor(pa, 4, 64);
      pb += __shfl_xor(pb, 1, 64); pb += __shfl_xor(pb, 2, 64); pb += __shfl_xor(pb, 4, 64);
      if ((lane & 7) == 0){ E[w][s][h] = pa; E[w][s+1][h] = pb; }
    }
    if (s < cnt){
      int ja = idxl[w][s];
      u32x2 ka = *(const u32x2*)(qkv + ((long)(b*Nn + ja))*768 + 256 + lane*4);
      float pa = qreg[0]*bf2f((u16)(ka[0]&0xffff)) + qreg[1]*bf2f((u16)(ka[0]>>16))
               + qreg[2]*bf2f((u16)(ka[1]&0xffff)) + qreg[3]*bf2f((u16)(ka[1]>>16));
      pa += __shfl_xor(pa, 1, 64); pa += __shfl_xor(pa, 2, 64); pa += __shfl_xor(pa, 4, 64);
      if ((lane & 7) == 0) E[w][s][h] = pa;
    }
  }
  __syncthreads();

  // ---- Phase B: per-head max/sum; lane = h*8+k owns slots s==k (mod 8) ----
  { const int h = lane >> 3, k = lane & 7;
    float m = -3.0e38f;
    for (int s = k; s < cnt; s += 8) m = fmaxf(m, E[w][s][h]);
    m = fmaxf(m, __shfl_xor(m, 1, 64));
    m = fmaxf(m, __shfl_xor(m, 2, 64));
    m = fmaxf(m, __shfl_xor(m, 4, 64));
    float l = 0.f;
    for (int s = k; s < cnt; s += 8){
      float e = __expf(E[w][s][h] - m);
      E[w][s][h] = e; l += e;
    }
    l += __shfl_xor(l, 1, 64);
    l += __shfl_xor(l, 2, 64);
    l += __shfl_xor(l, 4, 64);
    if (k == 0) invl[w][h] = 1.f / l;
  }
  __syncthreads();

  // ---- Phase C: amv[s] = 0.125 * sum_h E[s][h]*invl[h] ----
  { f32x4 i0v = *(f32x4*)&invl[w][0], i1v = *(f32x4*)&invl[w][4];
    for (int s = lane; s < cnt; s += 64){
      f32x4 e0 = *(f32x4*)&E[w][s][0], e1 = *(f32x4*)&E[w][s][4];
      float a = e0[0]*i0v[0] + e0[1]*i0v[1] + e0[2]*i0v[2] + e0[3]*i0v[3]
              + e1[0]*i1v[0] + e1[1]*i1v[1] + e1[2]*i1v[2] + e1[3]*i1v[3];
      amv[((long)(b*Nn + i))*CAP + s] = a * 0.125f;
    }
  }

  // ---- Phase D: PV; lane owns 4 output dims of head h = lane>>3 (coalesced V rows) ----
  { const int d0 = lane * 4, h = lane >> 3;
    f32x4 acc = {0.f, 0.f, 0.f, 0.f};
    for (int s = 0; s < cnt; ++s){
      int j = idxl[w][s];
      float ev = E[w][s][h];
      u32x2 vv = *(const u32x2*)(qkv + ((long)(b*Nn + j)) * 768 + 512 + d0);
      acc[0] += ev * bf2f((u16)(vv[0] & 0xffff));
      acc[1] += ev * bf2f((u16)(vv[0] >> 16));
      acc[2] += ev * bf2f((u16)(vv[1] & 0xffff));
      acc[3] += ev * bf2f((u16)(vv[1] >> 16));
    }
    float nl = invl[w][h];
    u32x2 pb;
    pb[0] = (u32)f2bf(acc[0]*nl) | ((u32)f2bf(acc[1]*nl) << 16);
    pb[1] = (u32)f2bf(acc[2]*nl) | ((u32)f2bf(acc[3]*nl) << 16);
    *(u32x2*)(ob + ((long)(b*Nn + i)) * 256 + d0) = pb;
  }
}

// ---------------- sparse chain 1 v2: 4 rows/block, wave-per-row, staged metadata ----------------
// grid (256, 8): i0 = blockIdx.x*4, b = blockIdx.y
__global__ __launch_bounds__(256) void sp_gemm1(
    const float* __restrict__ amv1, const float* __restrict__ amv0,
    const u16* __restrict__ idxg, const int* __restrict__ cntg,
    u16* __restrict__ P1)                 // [B*N][1024] bf16
{
  __shared__ float accum[4][1024];
  __shared__ u16 idxl[4][CAP];
  __shared__ u16 cjl[4][CAP];
  __shared__ float v1l[4][CAP];
  __shared__ int cntl[4];
  const int b = blockIdx.y, i0 = blockIdx.x * 4, tid = threadIdx.x;
  const int w = tid >> 6, lane = tid & 63;
  if (tid < 4) cntl[tid] = cntg[i0 + tid];
  for (int s = tid; s < 4*CAP; s += 256){
    int r = s / CAP, ss = s - r*CAP;
    idxl[r][ss] = idxg[(long)(i0 + r)*CAP + ss];
    v1l[r][ss]  = amv1[((long)(b*Nn + i0 + r))*CAP + ss];
  }
  { float* a = &accum[0][0];
    f32x4 z = {0.f,0.f,0.f,0.f};
    for (int t = tid*4; t < 4096; t += 1024) *(f32x4*)&a[t] = z; }
  __syncthreads();
  // stage neighbor counts (parallel, kills mid-chain scalar load)
  for (int s = tid; s < 4*CAP; s += 256){
    int r = s / CAP, ss = s - r*CAP;
    cjl[r][ss] = (ss < cntl[r]) ? (u16)cntg[idxl[r][ss]] : (u16)0;
  }
  __syncthreads();
  const int cnt = cntl[w];
  for (int s = 0; s < cnt; ++s){
    int j  = idxl[w][s];
    int cj = cjl[w][s];
    float vs = v1l[w][s];
    if (lane < cj){
      int col = idxg[(long)j*CAP + lane];
      atomicAdd(&accum[w][col], vs * amv0[((long)(b*Nn + j))*CAP + lane]);
    }
    if (cj > 64 && lane + 64 < cj){
      int col = idxg[(long)j*CAP + lane + 64];
      atomicAdd(&accum[w][col], vs * amv0[((long)(b*Nn + j))*CAP + lane + 64]);
    }
  }
  __syncthreads();
  const float* af = &accum[0][0];
  u16* dst = P1 + ((long)(b*Nn + i0))*1024;
  #pragma unroll
  for (int p = 0; p < 2; ++p){
    int base = p*2048 + tid*8;
    u32x4 pb;
    #pragma unroll
    for (int q = 0; q < 4; ++q)
      pb[q] = (u32)f2bf(af[base + 2*q]) | ((u32)f2bf(af[base + 2*q + 1]) << 16);
    *(u32x4*)(dst + base) = pb;
  }
}

// ---------------- sparse chain 2 ----------------
__global__ __launch_bounds__(256) void sp_gemm2(
    const float* __restrict__ amv2, const u16* __restrict__ P1,
    const u16* __restrict__ idxg, const int* __restrict__ cntg,
    float* __restrict__ out)              // [B*N][1024] f32 (d_out atten)
{
  __shared__ u16 idxl[CAP];
  __shared__ float v2[CAP];
  const int b = blockIdx.y, i = blockIdx.x, tid = threadIdx.x;
  const int cnt = cntg[i];
  if (tid < CAP){
    idxl[tid] = idxg[(long)i*CAP + tid];
    v2[tid]   = amv2[((long)(b*Nn + i))*CAP + tid];
  }
  __syncthreads();
  f32x4 acc = {0.f, 0.f, 0.f, 0.f};
  const int c0 = tid * 4;
  for (int s = 0; s < cnt; ++s){
    int j = idxl[s];
    float ev = v2[s];
    u32x2 vv = *(const u32x2*)(P1 + ((long)(b*Nn + j))*1024 + c0);
    acc[0] += ev * bf2f((u16)(vv[0] & 0xffff));
    acc[1] += ev * bf2f((u16)(vv[0] >> 16));
    acc[2] += ev * bf2f((u16)(vv[1] & 0xffff));
    acc[3] += ev * bf2f((u16)(vv[1] >> 16));
  }
  *(f32x4*)(out + ((long)(b*Nn + i))*1024 + c0) = acc;
}

// ---------------- residual + layernorm ----------------
__global__ __launch_bounds__(256) void ln_kernel(
    const float* __restrict__ hin, const float* __restrict__ y,
    float* __restrict__ hout, u16* __restrict__ hb, float* __restrict__ outf,
    const float* __restrict__ g, const float* __restrict__ be)
{
  int row  = blockIdx.x * 4 + (threadIdx.x >> 6);
  int lane = threadIdx.x & 63;
  f32x4 v = *(const f32x4*)(hin + (long)row*Dd + lane*4)
          + *(const f32x4*)(y   + (long)row*Dd + lane*4);
  float s = v[0] + v[1] + v[2] + v[3];
  #pragma unroll
  for (int off = 32; off; off >>= 1) s += __shfl_xor(s, off, 64);
  float mu = s * (1.f/256.f);
  f32x4 d = v - mu;
  float q2 = d[0]*d[0] + d[1]*d[1] + d[2]*d[2] + d[3]*d[3];
  #pragma unroll
  for (int off = 32; off; off >>= 1) q2 += __shfl_xor(q2, off, 64);
  float rs = rsqrtf(q2 * (1.f/256.f) + 1e-5f);
  f32x4 ov;
  #pragma unroll
  for (int p = 0; p < 4; ++p)
    ov[p] = d[p] * rs * g[lane*4 + p] + be[lane*4 + p];
  *(f32x4*)(hout + (long)row*Dd + lane*4) = ov;
  if (hb){
    u32x2 pb;
    pb[0] = (u32)f2bf(ov[0]) | ((u32)f2bf(ov[1]) << 16);
    pb[1] = (u32)f2bf(ov[2]) | ((u32)f2bf(ov[3]) << 16);
    *(u32x2*)(hb + (long)row*Dd + lane*4) = pb;
  }
  if (outf)
    *(f32x4*)(outf + (long)row*Dd + lane*4) = ov;
}

extern "C" void kernel_launch(void* const* d_in, const int* in_sizes, int n_in,
                              void* d_out, int out_size, void* d_ws, size_t ws_size,
                              hipStream_t stream)
{
  (void)in_sizes; (void)n_in; (void)out_size; (void)ws_size;
  const float* x   = (const float*)d_in[0];
  const float* adj = (const float*)d_in[1];
  const float* W0  = (const float*)d_in[2];
  const float* Wq  = (const float*)d_in[3];
  const float* bq  = (const float*)d_in[4];
  const float* Wk  = (const float*)d_in[5];
  const float* bk  = (const float*)d_in[6];
  const float* Wv  = (const float*)d_in[7];
  const float* bv  = (const float*)d_in[8];
  const float* Wo  = (const float*)d_in[9];
  const float* bo  = (const float*)d_in[10];
  const float* gm  = (const float*)d_in[11];
  const float* bt  = (const float*)d_in[12];
  float* outf  = (float*)d_out;                 // f32 h region [8,1024,256]
  float* outat = outf + (long)Bb * Nn * Dd;     // f32 atten region [8,1024,1024]

  // ---- workspace (~67MB < proven 92MB) ----
  char* w = (char*)d_ws;
  u16* W0b  = (u16*)w; w += 131072;
  u16* Wqb  = (u16*)w; w += 393216;             // Wq|Wk|Wv|Wo contiguous (conv_w4)
  u16* Wkb  = (u16*)w; w += 393216;
  u16* Wvb  = (u16*)w; w += 393216;
  u16* Wob  = (u16*)w; w += 393216;
  float* bqkv = (float*)w; w += 9216;           // [3][768]
  u32* bitsg = (u32*)w; w += 131072;
  u16* idxg  = (u16*)w; w += 1024*CAP*2;        // 192KB
  int* cntg  = (int*)w; w += 4096;
  u16* xb  = (u16*)w; w += 4194304;
  u16* hb  = (u16*)w; w += 4194304;
  u16* qkv = (u16*)w; w += (long)Bb*Nn*768*2;   // 12MB
  u16* ob  = (u16*)w; w += 4194304;
  float* hbuf = (float*)w; w += 8388608;
  float* ybuf = (float*)w; w += 8388608;
  float* amv0 = (float*)w; w += (long)Bb*Nn*CAP*4;  // 3MB each
  float* amv1 = (float*)w; w += (long)Bb*Nn*CAP*4;
  float* amv2 = (float*)w; w += (long)Bb*Nn*CAP*4;
  u16* P1   = (u16*)w; w += 16777216;           // [8][1024][1024] bf16
  float* amvl[3] = {amv0, amv1, amv2};

  dim3 blk(256);
  f32_to_bf16<<<2048, blk, 0, stream>>>(x,  xb,  2097152);
  f32_to_bf16<<<64,   blk, 0, stream>>>(W0, W0b, 65536);
  conv_w4<<<768, blk, 0, stream>>>(Wq, Wk, Wv, Wo, Wqb);
  bias_concat<<<1, blk, 0, stream>>>(bq, bk, bv, bqkv);
  adj_to_bits<<<128, blk, 0, stream>>>(adj, bitsg);
  nbr_build<<<4, blk, 0, stream>>>(bitsg, idxg, cntg);

  // input projection: h = x @ W0^T  (f32 + bf16)
  gemm_bt<false,false,true,true><<<dim3(2,64,1), blk, 0, stream>>>(
      xb, 256, 0, W0b, 256, 0, hbuf, hb, 256, 0, 256, nullptr, 0, nullptr);

  for (int l = 0; l < 3; ++l){
    // fused q|k|v projection: grid z selects weight section and C column offset
    gemm_bt<true,false,false,true><<<dim3(2,64,3), blk, 0, stream>>>(
        hb, 256, 0, Wqb + (long)l*65536, 256, 196608,
        nullptr, qkv, 768, 256, 256, bqkv + l*768, 256, nullptr);
    // sparse attention (grid (256,8): consecutive blocks share batch)
    attn_sparse<<<dim3(256,8), blk, 0, stream>>>(qkv, ob, idxg, cntg, amvl[l]);
    // y = o @ Wo^T + bo (f32)
    gemm_bt<true,false,true,false><<<dim3(2,64,1), blk, 0, stream>>>(
        ob, 256, 0, Wob + (long)l*65536, 256, 0, ybuf, nullptr, 256, 0, 256,
        bo + l*256, 0, nullptr);
    // h = LN(h + y)
    ln_kernel<<<dim3(2048), blk, 0, stream>>>(
        hbuf, ybuf, hbuf, (l < 2 ? hb : nullptr), (l < 2 ? nullptr : outf),
        gm + l*256, bt + l*256);
    // sparse chain
    if (l == 1)
      sp_gemm1<<<dim3(256,8), blk, 0, stream>>>(amv1, amv0, idxg, cntg, P1);
    if (l == 2)
      sp_gemm2<<<dim3(1024,8), blk, 0, stream>>>(amv2, P1, idxg, cntg, outat);
  }
}

// Round 12
// 305.699 us; speedup vs baseline: 3.3396x; 1.0441x over previous
//
#include <hip/hip_runtime.h>

typedef unsigned short u16;
typedef unsigned int   u32;
typedef float  f32x4  __attribute__((ext_vector_type(4)));
typedef __bf16 bf16x8 __attribute__((ext_vector_type(8)));
typedef u32    u32x4  __attribute__((ext_vector_type(4)));
typedef u32    u32x2  __attribute__((ext_vector_type(2)));

#define Bb  8
#define Nn  1024
#define Dd  256
#define Hh  8
#define HDd 32
#define CAP 96

__device__ __forceinline__ float bf2f(u16 s){
  u32 u = ((u32)s) << 16; float f; __builtin_memcpy(&f, &u, 4); return f;
}
__device__ __forceinline__ u16 f2bf(float f){
  u32 u; __builtin_memcpy(&u, &f, 4);
  u = (u + 0x7fffu + ((u >> 16) & 1u)) >> 16;
  return (u16)u;
}
__device__ __forceinline__ f32x4 mfma16(bf16x8 a, bf16x8 b, f32x4 c){
  return __builtin_amdgcn_mfma_f32_16x16x32_bf16(a, b, c, 0, 0, 0);
}
__device__ __forceinline__ bf16x8 ld_bf8(const u16* p){
  u32x4 u = *(const u32x4*)p; bf16x8 r; __builtin_memcpy(&r, &u, 16); return r;
}

// ---------------- f32 -> bf16 convert ----------------
__global__ void f32_to_bf16(const float* __restrict__ src, u16* __restrict__ dst, int n){
  int i = (blockIdx.x * 256 + threadIdx.x) * 4;
  if (i < n){
    f32x4 v = *(const f32x4*)(src + i);
    u32x2 p;
    p[0] = (u32)f2bf(v[0]) | ((u32)f2bf(v[1]) << 16);
    p[1] = (u32)f2bf(v[2]) | ((u32)f2bf(v[3]) << 16);
    *(u32x2*)(dst + i) = p;
  }
}

// ---------------- 4-weight convert ----------------
__global__ void conv_w4(const float* __restrict__ wq, const float* __restrict__ wk,
                        const float* __restrict__ wv, const float* __restrict__ wo,
                        u16* __restrict__ dst){
  int g = blockIdx.x * 256 + threadIdx.x;      // 0..196607
  int sec = g / 49152, off = (g - sec * 49152) * 4;
  const float* src = (sec == 0 ? wq : sec == 1 ? wk : sec == 2 ? wv : wo);
  f32x4 v = *(const f32x4*)(src + off);
  u32x2 p;
  p[0] = (u32)f2bf(v[0]) | ((u32)f2bf(v[1]) << 16);
  p[1] = (u32)f2bf(v[2]) | ((u32)f2bf(v[3]) << 16);
  *(u32x2*)(dst + sec * 196608 + off) = p;
}

// ---------------- bias concat ----------------
__global__ void bias_concat(const float* __restrict__ bq, const float* __restrict__ bk,
                            const float* __restrict__ bv, float* __restrict__ bqkv){
  int t = threadIdx.x;   // 256
  for (int l = 0; l < 3; ++l){
    bqkv[l*768 +       t] = bq[l*256 + t];
    bqkv[l*768 + 256 + t] = bk[l*256 + t];
    bqkv[l*768 + 512 + t] = bv[l*256 + t];
  }
}

// ---------------- adj -> bitmask ----------------
__global__ void adj_to_bits(const float* __restrict__ adj, u32* __restrict__ bits){
  int w = blockIdx.x * 256 + threadIdx.x;        // word over [1024][32]
  const float* p = adj + (long)w * 32;
  u32 m = 0;
  #pragma unroll
  for (int t = 0; t < 32; t += 4){
    f32x4 v = *(const f32x4*)(p + t);
    if (v[0] != 0.f) m |= 1u << (t+0);
    if (v[1] != 0.f) m |= 1u << (t+1);
    if (v[2] != 0.f) m |= 1u << (t+2);
    if (v[3] != 0.f) m |= 1u << (t+3);
  }
  bits[w] = m;
}

// ---------------- neighbor list build (CSR, capacity CAP) ----------------
__global__ __launch_bounds__(256) void nbr_build(const u32* __restrict__ bits,
                                                 u16* __restrict__ idx, int* __restrict__ cnt){
  int i = blockIdx.x * 256 + threadIdx.x;        // grid 4
  int c = 0;
  for (int w = 0; w < 32; ++w){
    u32 wd = bits[i*32 + w];
    while (wd){
      int bi = __ffs(wd) - 1; wd &= wd - 1;
      if (c < CAP) idx[(long)i*CAP + c] = (u16)(w*32 + bi);
      ++c;
    }
  }
  cnt[i] = (c < CAP) ? c : CAP;
}

// ---------------- MFMA GEMM (VALIDATED R4-R10) ----------------
template<bool HBC, bool HBR, bool OF, bool OB>
__global__ __launch_bounds__(256,2) void gemm_bt(
    const u16* __restrict__ A, int lda, long sA,
    const u16* __restrict__ Bt, int ldb, long sB,
    float* __restrict__ Cf, u16* __restrict__ Cb, int ldc, long sC,
    int K, const float* __restrict__ bc, long sbc, const float* __restrict__ br)
{
  __shared__ u16 As[128][40];
  __shared__ u16 Bs[128][40];
  const int bz = blockIdx.z;
  const u16* Ap = A + (long)bz * sA;
  const u16* Bp = Bt + (long)bz * sB;
  const long co = (long)bz * sC;
  const int m0 = blockIdx.y * 128, n0 = blockIdx.x * 128;
  const int tid = threadIdx.x, wave = tid >> 6, lane = tid & 63;
  const int arow = lane & 15, agrp = lane >> 4;
  const int wr = (wave >> 1) * 64, wc = (wave & 1) * 64;
  const int srow = tid >> 1, sch = (tid & 1) * 16;
  const u16* ga = Ap + (long)(m0 + srow) * lda + sch;
  const u16* gb = Bp + (long)(n0 + srow) * ldb + sch;
  f32x4 acc[4][4] = {};
  for (int kb = 0; kb < K; kb += 32){
    u32x4 a0 = *(const u32x4*)ga; u32x4 a1 = *(const u32x4*)(ga + 8);
    u32x4 b0 = *(const u32x4*)gb; u32x4 b1 = *(const u32x4*)(gb + 8);
    __syncthreads();
    *(u32x4*)&As[srow][sch] = a0; *(u32x4*)&As[srow][sch + 8] = a1;
    *(u32x4*)&Bs[srow][sch] = b0; *(u32x4*)&Bs[srow][sch + 8] = b1;
    __syncthreads();
    ga += 32; gb += 32;
    bf16x8 af[4], bv[4];
    #pragma unroll
    for (int f = 0; f < 4; ++f){
      af[f] = ld_bf8(&As[wr + f*16 + arow][agrp*8]);
      bv[f] = ld_bf8(&Bs[wc + f*16 + arow][agrp*8]);
    }
    #pragma unroll
    for (int fm = 0; fm < 4; ++fm)
      #pragma unroll
      for (int fn = 0; fn < 4; ++fn)
        acc[fm][fn] = mfma16(af[fm], bv[fn], acc[fm][fn]);
  }
  #pragma unroll
  for (int fm = 0; fm < 4; ++fm){
    #pragma unroll
    for (int fn = 0; fn < 4; ++fn){
      int j = n0 + wc + fn*16 + arow;
      float badd = 0.f;
      if (HBC) badd = bc[(long)bz*sbc + j];
      #pragma unroll
      for (int r = 0; r < 4; ++r){
        int i = m0 + wr + fm*16 + agrp*4 + r;
        float v = acc[fm][fn][r] + badd;
        if (HBR) v += br[i];
        long idx = co + (long)i * ldc + j;
        if (OF) Cf[idx] = v;
        if (OB) Cb[idx] = f2bf(v);
      }
    }
  }
}

// ---------------- sparse attention v5: coalesced A + unrolled D ----------------
// grid (256, 8): i0 = blockIdx.x*4, b = blockIdx.y
__global__ __launch_bounds__(256) void attn_sparse(
    const u16* __restrict__ qkv,          // [B*N][768] bf16: q|k|v
    u16* __restrict__ ob,                 // [B*N][256] bf16
    const u16* __restrict__ idxg, const int* __restrict__ cntg,
    float* __restrict__ amv)              // [B*N][CAP] f32 (slots < cnt valid)
{
  __shared__ float qs[4][256];            // q rows, pre-scaled f32
  __shared__ float E[4][CAP][8];          // raw scores -> unnormalized exp
  __shared__ float invl[4][8];            // per-(row,head) 1/sum
  __shared__ u16   idxl[4][CAP];
  __shared__ int   cntl[4];
  const int b = blockIdx.y, i0 = blockIdx.x * 4;
  const int tid = threadIdx.x, w = tid >> 6, lane = tid & 63;
  const float SCALE = 0.17677669529663687f;   // 1/sqrt(32)

  { int e = tid * 4, rr = e >> 8, c = e & 255;
    u32x2 uv = *(const u32x2*)(qkv + ((long)(b*Nn + i0 + rr)) * 768 + c);
    qs[rr][c+0] = SCALE * bf2f((u16)(uv[0] & 0xffff));
    qs[rr][c+1] = SCALE * bf2f((u16)(uv[0] >> 16));
    qs[rr][c+2] = SCALE * bf2f((u16)(uv[1] & 0xffff));
    qs[rr][c+3] = SCALE * bf2f((u16)(uv[1] >> 16)); }
  for (int s = tid; s < 4*CAP; s += 256){
    int rr = s / CAP, ss = s - rr*CAP;
    idxl[rr][ss] = idxg[(long)(i0 + rr)*CAP + ss];
  }
  if (tid < 4) cntl[tid] = cntg[i0 + tid];
  __syncthreads();

  const int i = i0 + w;
  const int cnt = cntl[w];

  // ---- Phase A: wave iterates neighbors; coalesced 512B K-row reads; 8-lane reduce ----
  { const f32x4 qreg = *(const f32x4*)&qs[w][lane*4];
    const int h = lane >> 3;
    int s = 0;
    for (; s + 2 <= cnt; s += 2){
      int ja = idxl[w][s], jb = idxl[w][s+1];
      u32x2 ka = *(const u32x2*)(qkv + ((long)(b*Nn + ja))*768 + 256 + lane*4);
      u32x2 kb = *(const u32x2*)(qkv + ((long)(b*Nn + jb))*768 + 256 + lane*4);
      float pa = qreg[0]*bf2f((u16)(ka[0]&0xffff)) + qreg[1]*bf2f((u16)(ka[0]>>16))
               + qreg[2]*bf2f((u16)(ka[1]&0xffff)) + qreg[3]*bf2f((u16)(ka[1]>>16));
      float pb = qreg[0]*bf2f((u16)(kb[0]&0xffff)) + qreg[1]*bf2f((u16)(kb[0]>>16))
               + qreg[2]*bf2f((u16)(kb[1]&0xffff)) + qreg[3]*bf2f((u16)(kb[1]>>16));
      pa += __shfl_xor(pa, 1, 64); pa += __shfl_xor(pa, 2, 64); pa += __shfl_xor(pa, 4, 64);
      pb += __shfl_xor(pb, 1, 64); pb += __shfl_xor(pb, 2, 64); pb += __shfl_xor(pb, 4, 64);
      if ((lane & 7) == 0){ E[w][s][h] = pa; E[w][s+1][h] = pb; }
    }
    if (s < cnt){
      int ja = idxl[w][s];
      u32x2 ka = *(const u32x2*)(qkv + ((long)(b*Nn + ja))*768 + 256 + lane*4);
      float pa = qreg[0]*bf2f((u16)(ka[0]&0xffff)) + qreg[1]*bf2f((u16)(ka[0]>>16))
               + qreg[2]*bf2f((u16)(ka[1]&0xffff)) + qreg[3]*bf2f((u16)(ka[1]>>16));
      pa += __shfl_xor(pa, 1, 64); pa += __shfl_xor(pa, 2, 64); pa += __shfl_xor(pa, 4, 64);
      if ((lane & 7) == 0) E[w][s][h] = pa;
    }
  }
  __syncthreads();

  // ---- Phase B: per-head max/sum; lane = h*8+k owns slots s==k (mod 8) ----
  { const int h = lane >> 3, k = lane & 7;
    float m = -3.0e38f;
    for (int s = k; s < cnt; s += 8) m = fmaxf(m, E[w][s][h]);
    m = fmaxf(m, __shfl_xor(m, 1, 64));
    m = fmaxf(m, __shfl_xor(m, 2, 64));
    m = fmaxf(m, __shfl_xor(m, 4, 64));
    float l = 0.f;
    for (int s = k; s < cnt; s += 8){
      float e = __expf(E[w][s][h] - m);
      E[w][s][h] = e; l += e;
    }
    l += __shfl_xor(l, 1, 64);
    l += __shfl_xor(l, 2, 64);
    l += __shfl_xor(l, 4, 64);
    if (k == 0) invl[w][h] = 1.f / l;
  }
  __syncthreads();

  // ---- Phase C: amv[s] = 0.125 * sum_h E[s][h]*invl[h] ----
  { f32x4 i0v = *(f32x4*)&invl[w][0], i1v = *(f32x4*)&invl[w][4];
    for (int s = lane; s < cnt; s += 64){
      f32x4 e0 = *(f32x4*)&E[w][s][0], e1 = *(f32x4*)&E[w][s][4];
      float a = e0[0]*i0v[0] + e0[1]*i0v[1] + e0[2]*i0v[2] + e0[3]*i0v[3]
              + e1[0]*i1v[0] + e1[1]*i1v[1] + e1[2]*i1v[2] + e1[3]*i1v[3];
      amv[((long)(b*Nn + i))*CAP + s] = a * 0.125f;
    }
  }

  // ---- Phase D: PV, 2-way unrolled (MLP) ----
  { const int d0 = lane * 4, h = lane >> 3;
    f32x4 acc = {0.f, 0.f, 0.f, 0.f};
    int s = 0;
    for (; s + 2 <= cnt; s += 2){
      int ja = idxl[w][s], jb = idxl[w][s+1];
      u32x2 va = *(const u32x2*)(qkv + ((long)(b*Nn + ja)) * 768 + 512 + d0);
      u32x2 vb = *(const u32x2*)(qkv + ((long)(b*Nn + jb)) * 768 + 512 + d0);
      float ea = E[w][s][h], eb = E[w][s+1][h];
      acc[0] += ea * bf2f((u16)(va[0] & 0xffff)) + eb * bf2f((u16)(vb[0] & 0xffff));
      acc[1] += ea * bf2f((u16)(va[0] >> 16))    + eb * bf2f((u16)(vb[0] >> 16));
      acc[2] += ea * bf2f((u16)(va[1] & 0xffff)) + eb * bf2f((u16)(vb[1] & 0xffff));
      acc[3] += ea * bf2f((u16)(va[1] >> 16))    + eb * bf2f((u16)(vb[1] >> 16));
    }
    if (s < cnt){
      int ja = idxl[w][s];
      u32x2 va = *(const u32x2*)(qkv + ((long)(b*Nn + ja)) * 768 + 512 + d0);
      float ea = E[w][s][h];
      acc[0] += ea * bf2f((u16)(va[0] & 0xffff));
      acc[1] += ea * bf2f((u16)(va[0] >> 16));
      acc[2] += ea * bf2f((u16)(va[1] & 0xffff));
      acc[3] += ea * bf2f((u16)(va[1] >> 16));
    }
    float nl = invl[w][h];
    u32x2 pb;
    pb[0] = (u32)f2bf(acc[0]*nl) | ((u32)f2bf(acc[1]*nl) << 16);
    pb[1] = (u32)f2bf(acc[2]*nl) | ((u32)f2bf(acc[3]*nl) << 16);
    *(u32x2*)(ob + ((long)(b*Nn + i)) * 256 + d0) = pb;
  }
}

// ---------------- sparse chain 1 v3: flat pairs + staged cj + 2-way unroll ----------------
// grid (1024, 8): one row per block
__global__ __launch_bounds__(256) void sp_gemm1(
    const float* __restrict__ amv1, const float* __restrict__ amv0,
    const u16* __restrict__ idxg, const int* __restrict__ cntg,
    u16* __restrict__ P1)                 // [B*N][1024] bf16
{
  __shared__ float accum[1024];
  __shared__ u16 idxl[CAP];
  __shared__ u16 cjl[CAP];
  __shared__ float v1[CAP];
  const int b = blockIdx.y, i = blockIdx.x, tid = threadIdx.x;
  { f32x4 z = {0.f,0.f,0.f,0.f}; *(f32x4*)&accum[tid*4] = z; }
  const int cnt = cntg[i];
  if (tid < CAP){
    idxl[tid] = idxg[(long)i*CAP + tid];
    v1[tid]   = amv1[((long)(b*Nn + i))*CAP + tid];
  }
  __syncthreads();
  if (tid < CAP)
    cjl[tid] = (tid < cnt) ? (u16)cntg[idxl[tid]] : (u16)0;
  __syncthreads();
  const int npairs = cnt * 64;
  for (int p = tid; p < npairs; p += 512){
    // pair A
    const int sa = p >> 6, ta = p & 63;
    const int ja = idxl[sa], ca = cjl[sa];
    const float va = v1[sa];
    int colA = 0, colA2 = 0; float prA = 0.f, prA2 = 0.f;
    const bool dA  = ta < ca;
    const bool dA2 = ta + 64 < ca;
    if (dA){  colA  = idxg[(long)ja*CAP + ta];
              prA   = va * amv0[((long)(b*Nn + ja))*CAP + ta]; }
    if (dA2){ colA2 = idxg[(long)ja*CAP + ta + 64];
              prA2  = va * amv0[((long)(b*Nn + ja))*CAP + ta + 64]; }
    // pair B
    const int pb = p + 256;
    const bool hasB = pb < npairs;
    const int sb = pb >> 6, tb = pb & 63;
    int jb = 0, cb = 0; float vb = 0.f;
    if (hasB){ jb = idxl[sb]; cb = cjl[sb]; vb = v1[sb]; }
    int colB = 0, colB2 = 0; float prB = 0.f, prB2 = 0.f;
    const bool dB  = hasB && tb < cb;
    const bool dB2 = hasB && tb + 64 < cb;
    if (dB){  colB  = idxg[(long)jb*CAP + tb];
              prB   = vb * amv0[((long)(b*Nn + jb))*CAP + tb]; }
    if (dB2){ colB2 = idxg[(long)jb*CAP + tb + 64];
              prB2  = vb * amv0[((long)(b*Nn + jb))*CAP + tb + 64]; }
    // commit
    if (dA)  atomicAdd(&accum[colA],  prA);
    if (dA2) atomicAdd(&accum[colA2], prA2);
    if (dB)  atomicAdd(&accum[colB],  prB);
    if (dB2) atomicAdd(&accum[colB2], prB2);
  }
  __syncthreads();
  int c0 = tid * 4;
  u32x2 pb;
  pb[0] = (u32)f2bf(accum[c0])   | ((u32)f2bf(accum[c0+1]) << 16);
  pb[1] = (u32)f2bf(accum[c0+2]) | ((u32)f2bf(accum[c0+3]) << 16);
  *(u32x2*)(P1 + ((long)(b*Nn + i))*1024 + c0) = pb;
}

// ---------------- sparse chain 2: 2-way unrolled gather ----------------
__global__ __launch_bounds__(256) void sp_gemm2(
    const float* __restrict__ amv2, const u16* __restrict__ P1,
    const u16* __restrict__ idxg, const int* __restrict__ cntg,
    float* __restrict__ out)              // [B*N][1024] f32 (d_out atten)
{
  __shared__ u16 idxl[CAP];
  __shared__ float v2[CAP];
  const int b = blockIdx.y, i = blockIdx.x, tid = threadIdx.x;
  const int cnt = cntg[i];
  if (tid < CAP){
    idxl[tid] = idxg[(long)i*CAP + tid];
    v2[tid]   = amv2[((long)(b*Nn + i))*CAP + tid];
  }
  __syncthreads();
  f32x4 acc = {0.f, 0.f, 0.f, 0.f};
  const int c0 = tid * 4;
  int s = 0;
  for (; s + 2 <= cnt; s += 2){
    int ja = idxl[s], jb = idxl[s+1];
    float ea = v2[s], eb = v2[s+1];
    u32x2 va = *(const u32x2*)(P1 + ((long)(b*Nn + ja))*1024 + c0);
    u32x2 vb = *(const u32x2*)(P1 + ((long)(b*Nn + jb))*1024 + c0);
    acc[0] += ea * bf2f((u16)(va[0] & 0xffff)) + eb * bf2f((u16)(vb[0] & 0xffff));
    acc[1] += ea * bf2f((u16)(va[0] >> 16))    + eb * bf2f((u16)(vb[0] >> 16));
    acc[2] += ea * bf2f((u16)(va[1] & 0xffff)) + eb * bf2f((u16)(vb[1] & 0xffff));
    acc[3] += ea * bf2f((u16)(va[1] >> 16))    + eb * bf2f((u16)(vb[1] >> 16));
  }
  if (s < cnt){
    int ja = idxl[s];
    float ea = v2[s];
    u32x2 va = *(const u32x2*)(P1 + ((long)(b*Nn + ja))*1024 + c0);
    acc[0] += ea * bf2f((u16)(va[0] & 0xffff));
    acc[1] += ea * bf2f((u16)(va[0] >> 16));
    acc[2] += ea * bf2f((u16)(va[1] & 0xffff));
    acc[3] += ea * bf2f((u16)(va[1] >> 16));
  }
  *(f32x4*)(out + ((long)(b*Nn + i))*1024 + c0) = acc;
}

// ---------------- residual + layernorm ----------------
__global__ __launch_bounds__(256) void ln_kernel(
    const float* __restrict__ hin, const float* __restrict__ y,
    float* __restrict__ hout, u16* __restrict__ hb, float* __restrict__ outf,
    const float* __restrict__ g, const float* __restrict__ be)
{
  int row  = blockIdx.x * 4 + (threadIdx.x >> 6);
  int lane = threadIdx.x & 63;
  f32x4 v = *(const f32x4*)(hin + (long)row*Dd + lane*4)
          + *(const f32x4*)(y   + (long)row*Dd + lane*4);
  float s = v[0] + v[1] + v[2] + v[3];
  #pragma unroll
  for (int off = 32; off; off >>= 1) s += __shfl_xor(s, off, 64);
  float mu = s * (1.f/256.f);
  f32x4 d = v - mu;
  float q2 = d[0]*d[0] + d[1]*d[1] + d[2]*d[2] + d[3]*d[3];
  #pragma unroll
  for (int off = 32; off; off >>= 1) q2 += __shfl_xor(q2, off, 64);
  float rs = rsqrtf(q2 * (1.f/256.f) + 1e-5f);
  f32x4 ov;
  #pragma unroll
  for (int p = 0; p < 4; ++p)
    ov[p] = d[p] * rs * g[lane*4 + p] + be[lane*4 + p];
  *(f32x4*)(hout + (long)row*Dd + lane*4) = ov;
  if (hb){
    u32x2 pb;
    pb[0] = (u32)f2bf(ov[0]) | ((u32)f2bf(ov[1]) << 16);
    pb[1] = (u32)f2bf(ov[2]) | ((u32)f2bf(ov[3]) << 16);
    *(u32x2*)(hb + (long)row*Dd + lane*4) = pb;
  }
  if (outf)
    *(f32x4*)(outf + (long)row*Dd + lane*4) = ov;
}

extern "C" void kernel_launch(void* const* d_in, const int* in_sizes, int n_in,
                              void* d_out, int out_size, void* d_ws, size_t ws_size,
                              hipStream_t stream)
{
  (void)in_sizes; (void)n_in; (void)out_size; (void)ws_size;
  const float* x   = (const float*)d_in[0];
  const float* adj = (const float*)d_in[1];
  const float* W0  = (const float*)d_in[2];
  const float* Wq  = (const float*)d_in[3];
  const float* bq  = (const float*)d_in[4];
  const float* Wk  = (const float*)d_in[5];
  const float* bk  = (const float*)d_in[6];
  const float* Wv  = (const float*)d_in[7];
  const float* bv  = (const float*)d_in[8];
  const float* Wo  = (const float*)d_in[9];
  const float* bo  = (const float*)d_in[10];
  const float* gm  = (const float*)d_in[11];
  const float* bt  = (const float*)d_in[12];
  float* outf  = (float*)d_out;                 // f32 h region [8,1024,256]
  float* outat = outf + (long)Bb * Nn * Dd;     // f32 atten region [8,1024,1024]

  // ---- workspace (~67MB < proven 92MB) ----
  char* w = (char*)d_ws;
  u16* W0b  = (u16*)w; w += 131072;
  u16* Wqb  = (u16*)w; w += 393216;             // Wq|Wk|Wv|Wo contiguous (conv_w4)
  u16* Wkb  = (u16*)w; w += 393216;
  u16* Wvb  = (u16*)w; w += 393216;
  u16* Wob  = (u16*)w; w += 393216;
  float* bqkv = (float*)w; w += 9216;           // [3][768]
  u32* bitsg = (u32*)w; w += 131072;
  u16* idxg  = (u16*)w; w += 1024*CAP*2;        // 192KB
  int* cntg  = (int*)w; w += 4096;
  u16* xb  = (u16*)w; w += 4194304;
  u16* hb  = (u16*)w; w += 4194304;
  u16* qkv = (u16*)w; w += (long)Bb*Nn*768*2;   // 12MB
  u16* ob  = (u16*)w; w += 4194304;
  float* hbuf = (float*)w; w += 8388608;
  float* ybuf = (float*)w; w += 8388608;
  float* amv0 = (float*)w; w += (long)Bb*Nn*CAP*4;  // 3MB each
  float* amv1 = (float*)w; w += (long)Bb*Nn*CAP*4;
  float* amv2 = (float*)w; w += (long)Bb*Nn*CAP*4;
  u16* P1   = (u16*)w; w += 16777216;           // [8][1024][1024] bf16
  float* amvl[3] = {amv0, amv1, amv2};

  dim3 blk(256);
  f32_to_bf16<<<2048, blk, 0, stream>>>(x,  xb,  2097152);
  f32_to_bf16<<<64,   blk, 0, stream>>>(W0, W0b, 65536);
  conv_w4<<<768, blk, 0, stream>>>(Wq, Wk, Wv, Wo, Wqb);
  bias_concat<<<1, blk, 0, stream>>>(bq, bk, bv, bqkv);
  adj_to_bits<<<128, blk, 0, stream>>>(adj, bitsg);
  nbr_build<<<4, blk, 0, stream>>>(bitsg, idxg, cntg);

  // input projection: h = x @ W0^T  (f32 + bf16)
  gemm_bt<false,false,true,true><<<dim3(2,64,1), blk, 0, stream>>>(
      xb, 256, 0, W0b, 256, 0, hbuf, hb, 256, 0, 256, nullptr, 0, nullptr);

  for (int l = 0; l < 3; ++l){
    // fused q|k|v projection
    gemm_bt<true,false,false,true><<<dim3(2,64,3), blk, 0, stream>>>(
        hb, 256, 0, Wqb + (long)l*65536, 256, 196608,
        nullptr, qkv, 768, 256, 256, bqkv + l*768, 256, nullptr);
    // sparse attention
    attn_sparse<<<dim3(256,8), blk, 0, stream>>>(qkv, ob, idxg, cntg, amvl[l]);
    // y = o @ Wo^T + bo (f32)
    gemm_bt<true,false,true,false><<<dim3(2,64,1), blk, 0, stream>>>(
        ob, 256, 0, Wob + (long)l*65536, 256, 0, ybuf, nullptr, 256, 0, 256,
        bo + l*256, 0, nullptr);
    // h = LN(h + y)
    ln_kernel<<<dim3(2048), blk, 0, stream>>>(
        hbuf, ybuf, hbuf, (l < 2 ? hb : nullptr), (l < 2 ? nullptr : outf),
        gm + l*256, bt + l*256);
    // sparse chain
    if (l == 1)
      sp_gemm1<<<dim3(1024,8), blk, 0, stream>>>(amv1, amv0, idxg, cntg, P1);
    if (l == 2)
      sp_gemm2<<<dim3(1024,8), blk, 0, stream>>>(amv2, P1, idxg, cntg, outat);
  }
}

// Round 13
// 287.056 us; speedup vs baseline: 3.5565x; 1.0649x over previous
//
#include <hip/hip_runtime.h>

typedef unsigned short u16;
typedef unsigned int   u32;
typedef float  f32x4  __attribute__((ext_vector_type(4)));
typedef __bf16 bf16x8 __attribute__((ext_vector_type(8)));
typedef u32    u32x4  __attribute__((ext_vector_type(4)));
typedef u32    u32x2  __attribute__((ext_vector_type(2)));

#define Bb  8
#define Nn  1024
#define Dd  256
#define Hh  8
#define HDd 32
#define CAP 96

__device__ __forceinline__ float bf2f(u16 s){
  u32 u = ((u32)s) << 16; float f; __builtin_memcpy(&f, &u, 4); return f;
}
__device__ __forceinline__ u16 f2bf(float f){
  u32 u; __builtin_memcpy(&u, &f, 4);
  u = (u + 0x7fffu + ((u >> 16) & 1u)) >> 16;
  return (u16)u;
}
__device__ __forceinline__ f32x4 mfma16(bf16x8 a, bf16x8 b, f32x4 c){
  return __builtin_amdgcn_mfma_f32_16x16x32_bf16(a, b, c, 0, 0, 0);
}
__device__ __forceinline__ bf16x8 ld_bf8(const u16* p){
  u32x4 u = *(const u32x4*)p; bf16x8 r; __builtin_memcpy(&r, &u, 16); return r;
}

// ---------------- f32 -> bf16 convert ----------------
__global__ void f32_to_bf16(const float* __restrict__ src, u16* __restrict__ dst, int n){
  int i = (blockIdx.x * 256 + threadIdx.x) * 4;
  if (i < n){
    f32x4 v = *(const f32x4*)(src + i);
    u32x2 p;
    p[0] = (u32)f2bf(v[0]) | ((u32)f2bf(v[1]) << 16);
    p[1] = (u32)f2bf(v[2]) | ((u32)f2bf(v[3]) << 16);
    *(u32x2*)(dst + i) = p;
  }
}

// ---------------- fused 5-weight convert + bias concat ----------------
// dst: W0(65536) | Wq(196608) | Wk | Wv | Wo  (contiguous bf16)
// block 832 handles bqkv concat.
__global__ void conv_w5(const float* __restrict__ w0, const float* __restrict__ wq,
                        const float* __restrict__ wk, const float* __restrict__ wv,
                        const float* __restrict__ wo, u16* __restrict__ dst,
                        const float* __restrict__ bq, const float* __restrict__ bk,
                        const float* __restrict__ bv, float* __restrict__ bqkv){
  if (blockIdx.x == 832){
    int t = threadIdx.x;
    for (int l = 0; l < 3; ++l){
      bqkv[l*768 +       t] = bq[l*256 + t];
      bqkv[l*768 + 256 + t] = bk[l*256 + t];
      bqkv[l*768 + 512 + t] = bv[l*256 + t];
    }
    return;
  }
  int g4 = (blockIdx.x * 256 + threadIdx.x) * 4;
  const float* src;
  int off;
  if (g4 < 65536){ src = w0; off = g4; }
  else {
    int g = g4 - 65536;
    int sec = g / 196608; off = g - sec * 196608;
    src = (sec == 0 ? wq : sec == 1 ? wk : sec == 2 ? wv : wo);
  }
  f32x4 v = *(const f32x4*)(src + off);
  u32x2 p;
  p[0] = (u32)f2bf(v[0]) | ((u32)f2bf(v[1]) << 16);
  p[1] = (u32)f2bf(v[2]) | ((u32)f2bf(v[3]) << 16);
  *(u32x2*)(dst + g4) = p;
}

// ---------------- adj -> bitmask ----------------
__global__ void adj_to_bits(const float* __restrict__ adj, u32* __restrict__ bits){
  int w = blockIdx.x * 256 + threadIdx.x;        // word over [1024][32]
  const float* p = adj + (long)w * 32;
  u32 m = 0;
  #pragma unroll
  for (int t = 0; t < 32; t += 4){
    f32x4 v = *(const f32x4*)(p + t);
    if (v[0] != 0.f) m |= 1u << (t+0);
    if (v[1] != 0.f) m |= 1u << (t+1);
    if (v[2] != 0.f) m |= 1u << (t+2);
    if (v[3] != 0.f) m |= 1u << (t+3);
  }
  bits[w] = m;
}

// ---------------- neighbor list build (CSR, capacity CAP) ----------------
__global__ __launch_bounds__(256) void nbr_build(const u32* __restrict__ bits,
                                                 u16* __restrict__ idx, int* __restrict__ cnt){
  int i = blockIdx.x * 256 + threadIdx.x;        // grid 4
  int c = 0;
  for (int w = 0; w < 32; ++w){
    u32 wd = bits[i*32 + w];
    while (wd){
      int bi = __ffs(wd) - 1; wd &= wd - 1;
      if (c < CAP) idx[(long)i*CAP + c] = (u16)(w*32 + bi);
      ++c;
    }
  }
  cnt[i] = (c < CAP) ? c : CAP;
}

// ---------------- MFMA GEMM (VALIDATED R4-R12) ----------------
template<bool HBC, bool HBR, bool OF, bool OB>
__global__ __launch_bounds__(256,2) void gemm_bt(
    const u16* __restrict__ A, int lda, long sA,
    const u16* __restrict__ Bt, int ldb, long sB,
    float* __restrict__ Cf, u16* __restrict__ Cb, int ldc, long sC,
    int K, const float* __restrict__ bc, long sbc, const float* __restrict__ br)
{
  __shared__ u16 As[128][40];
  __shared__ u16 Bs[128][40];
  const int bz = blockIdx.z;
  const u16* Ap = A + (long)bz * sA;
  const u16* Bp = Bt + (long)bz * sB;
  const long co = (long)bz * sC;
  const int m0 = blockIdx.y * 128, n0 = blockIdx.x * 128;
  const int tid = threadIdx.x, wave = tid >> 6, lane = tid & 63;
  const int arow = lane & 15, agrp = lane >> 4;
  const int wr = (wave >> 1) * 64, wc = (wave & 1) * 64;
  const int srow = tid >> 1, sch = (tid & 1) * 16;
  const u16* ga = Ap + (long)(m0 + srow) * lda + sch;
  const u16* gb = Bp + (long)(n0 + srow) * ldb + sch;
  f32x4 acc[4][4] = {};
  for (int kb = 0; kb < K; kb += 32){
    u32x4 a0 = *(const u32x4*)ga; u32x4 a1 = *(const u32x4*)(ga + 8);
    u32x4 b0 = *(const u32x4*)gb; u32x4 b1 = *(const u32x4*)(gb + 8);
    __syncthreads();
    *(u32x4*)&As[srow][sch] = a0; *(u32x4*)&As[srow][sch + 8] = a1;
    *(u32x4*)&Bs[srow][sch] = b0; *(u32x4*)&Bs[srow][sch + 8] = b1;
    __syncthreads();
    ga += 32; gb += 32;
    bf16x8 af[4], bv[4];
    #pragma unroll
    for (int f = 0; f < 4; ++f){
      af[f] = ld_bf8(&As[wr + f*16 + arow][agrp*8]);
      bv[f] = ld_bf8(&Bs[wc + f*16 + arow][agrp*8]);
    }
    #pragma unroll
    for (int fm = 0; fm < 4; ++fm)
      #pragma unroll
      for (int fn = 0; fn < 4; ++fn)
        acc[fm][fn] = mfma16(af[fm], bv[fn], acc[fm][fn]);
  }
  #pragma unroll
  for (int fm = 0; fm < 4; ++fm){
    #pragma unroll
    for (int fn = 0; fn < 4; ++fn){
      int j = n0 + wc + fn*16 + arow;
      float badd = 0.f;
      if (HBC) badd = bc[(long)bz*sbc + j];
      #pragma unroll
      for (int r = 0; r < 4; ++r){
        int i = m0 + wr + fm*16 + agrp*4 + r;
        float v = acc[fm][fn][r] + badd;
        if (HBR) v += br[i];
        long idx = co + (long)i * ldc + j;
        if (OF) Cf[idx] = v;
        if (OB) Cb[idx] = f2bf(v);
      }
    }
  }
}

// ---------------- sparse attention v6: coalesced A, unrolled D, dense-am option ----------------
// grid (256, 8): i0 = blockIdx.x*4, b = blockIdx.y
__global__ __launch_bounds__(256) void attn_sparse(
    const u16* __restrict__ qkv,          // [B*N][768] bf16: q|k|v
    u16* __restrict__ ob,                 // [B*N][256] bf16
    const u16* __restrict__ idxg, const int* __restrict__ cntg,
    float* __restrict__ amv,              // compact dst (dense==0)
    u16* __restrict__ amd, int dense)     // dense dst [B*N][1024] bf16 (dense==1)
{
  __shared__ float qs[4][256];            // q rows, pre-scaled f32
  __shared__ float E[4][CAP][8];          // raw scores -> unnormalized exp
  __shared__ float invl[4][8];            // per-(row,head) 1/sum
  __shared__ u16   idxl[4][CAP];
  __shared__ int   cntl[4];
  const int b = blockIdx.y, i0 = blockIdx.x * 4;
  const int tid = threadIdx.x, w = tid >> 6, lane = tid & 63;
  const float SCALE = 0.17677669529663687f;   // 1/sqrt(32)

  { int e = tid * 4, rr = e >> 8, c = e & 255;
    u32x2 uv = *(const u32x2*)(qkv + ((long)(b*Nn + i0 + rr)) * 768 + c);
    qs[rr][c+0] = SCALE * bf2f((u16)(uv[0] & 0xffff));
    qs[rr][c+1] = SCALE * bf2f((u16)(uv[0] >> 16));
    qs[rr][c+2] = SCALE * bf2f((u16)(uv[1] & 0xffff));
    qs[rr][c+3] = SCALE * bf2f((u16)(uv[1] >> 16)); }
  for (int s = tid; s < 4*CAP; s += 256){
    int rr = s / CAP, ss = s - rr*CAP;
    idxl[rr][ss] = idxg[(long)(i0 + rr)*CAP + ss];
  }
  if (tid < 4) cntl[tid] = cntg[i0 + tid];
  __syncthreads();

  const int i = i0 + w;
  const int cnt = cntl[w];

  // ---- Phase A: coalesced 512B K-row reads; 8-lane group reduce; 2-way unroll ----
  { const f32x4 qreg = *(const f32x4*)&qs[w][lane*4];
    const int h = lane >> 3;
    int s = 0;
    for (; s + 2 <= cnt; s += 2){
      int ja = idxl[w][s], jb = idxl[w][s+1];
      u32x2 ka = *(const u32x2*)(qkv + ((long)(b*Nn + ja))*768 + 256 + lane*4);
      u32x2 kb = *(const u32x2*)(qkv + ((long)(b*Nn + jb))*768 + 256 + lane*4);
      float pa = qreg[0]*bf2f((u16)(ka[0]&0xffff)) + qreg[1]*bf2f((u16)(ka[0]>>16))
               + qreg[2]*bf2f((u16)(ka[1]&0xffff)) + qreg[3]*bf2f((u16)(ka[1]>>16));
      float pb = qreg[0]*bf2f((u16)(kb[0]&0xffff)) + qreg[1]*bf2f((u16)(kb[0]>>16))
               + qreg[2]*bf2f((u16)(kb[1]&0xffff)) + qreg[3]*bf2f((u16)(kb[1]>>16));
      pa += __shfl_xor(pa, 1, 64); pa += __shfl_xor(pa, 2, 64); pa += __shfl_xor(pa, 4, 64);
      pb += __shfl_xor(pb, 1, 64); pb += __shfl_xor(pb, 2, 64); pb += __shfl_xor(pb, 4, 64);
      if ((lane & 7) == 0){ E[w][s][h] = pa; E[w][s+1][h] = pb; }
    }
    if (s < cnt){
      int ja = idxl[w][s];
      u32x2 ka = *(const u32x2*)(qkv + ((long)(b*Nn + ja))*768 + 256 + lane*4);
      float pa = qreg[0]*bf2f((u16)(ka[0]&0xffff)) + qreg[1]*bf2f((u16)(ka[0]>>16))
               + qreg[2]*bf2f((u16)(ka[1]&0xffff)) + qreg[3]*bf2f((u16)(ka[1]>>16));
      pa += __shfl_xor(pa, 1, 64); pa += __shfl_xor(pa, 2, 64); pa += __shfl_xor(pa, 4, 64);
      if ((lane & 7) == 0) E[w][s][h] = pa;
    }
  }
  __syncthreads();

  // ---- Phase B: per-head max/sum; lane = h*8+k owns slots s==k (mod 8) ----
  { const int h = lane >> 3, k = lane & 7;
    float m = -3.0e38f;
    for (int s = k; s < cnt; s += 8) m = fmaxf(m, E[w][s][h]);
    m = fmaxf(m, __shfl_xor(m, 1, 64));
    m = fmaxf(m, __shfl_xor(m, 2, 64));
    m = fmaxf(m, __shfl_xor(m, 4, 64));
    float l = 0.f;
    for (int s = k; s < cnt; s += 8){
      float e = __expf(E[w][s][h] - m);
      E[w][s][h] = e; l += e;
    }
    l += __shfl_xor(l, 1, 64);
    l += __shfl_xor(l, 2, 64);
    l += __shfl_xor(l, 4, 64);
    if (k == 0) invl[w][h] = 1.f / l;
  }
  __syncthreads();

  // ---- Phase C: a_mean; compact (amv) or dense scatter (amd) ----
  { f32x4 i0v = *(f32x4*)&invl[w][0], i1v = *(f32x4*)&invl[w][4];
    for (int s = lane; s < cnt; s += 64){
      f32x4 e0 = *(f32x4*)&E[w][s][0], e1 = *(f32x4*)&E[w][s][4];
      float a = e0[0]*i0v[0] + e0[1]*i0v[1] + e0[2]*i0v[2] + e0[3]*i0v[3]
              + e1[0]*i1v[0] + e1[1]*i1v[1] + e1[2]*i1v[2] + e1[3]*i1v[3];
      a *= 0.125f;
      if (dense) amd[((long)(b*Nn + i))*1024 + idxl[w][s]] = f2bf(a);
      else       amv[((long)(b*Nn + i))*CAP + s] = a;
    }
  }

  // ---- Phase D: PV, 2-way unrolled ----
  { const int d0 = lane * 4, h = lane >> 3;
    f32x4 acc = {0.f, 0.f, 0.f, 0.f};
    int s = 0;
    for (; s + 2 <= cnt; s += 2){
      int ja = idxl[w][s], jb = idxl[w][s+1];
      u32x2 va = *(const u32x2*)(qkv + ((long)(b*Nn + ja)) * 768 + 512 + d0);
      u32x2 vb = *(const u32x2*)(qkv + ((long)(b*Nn + jb)) * 768 + 512 + d0);
      float ea = E[w][s][h], eb = E[w][s+1][h];
      acc[0] += ea * bf2f((u16)(va[0] & 0xffff)) + eb * bf2f((u16)(vb[0] & 0xffff));
      acc[1] += ea * bf2f((u16)(va[0] >> 16))    + eb * bf2f((u16)(vb[0] >> 16));
      acc[2] += ea * bf2f((u16)(va[1] & 0xffff)) + eb * bf2f((u16)(vb[1] & 0xffff));
      acc[3] += ea * bf2f((u16)(va[1] >> 16))    + eb * bf2f((u16)(vb[1] >> 16));
    }
    if (s < cnt){
      int ja = idxl[w][s];
      u32x2 va = *(const u32x2*)(qkv + ((long)(b*Nn + ja)) * 768 + 512 + d0);
      float ea = E[w][s][h];
      acc[0] += ea * bf2f((u16)(va[0] & 0xffff));
      acc[1] += ea * bf2f((u16)(va[0] >> 16));
      acc[2] += ea * bf2f((u16)(va[1] & 0xffff));
      acc[3] += ea * bf2f((u16)(va[1] >> 16));
    }
    float nl = invl[w][h];
    u32x2 pb;
    pb[0] = (u32)f2bf(acc[0]*nl) | ((u32)f2bf(acc[1]*nl) << 16);
    pb[1] = (u32)f2bf(acc[2]*nl) | ((u32)f2bf(acc[3]*nl) << 16);
    *(u32x2*)(ob + ((long)(b*Nn + i)) * 256 + d0) = pb;
  }
}

// ---------------- sparse chain: dst_row[i] = sum_s wts[i][s] * rows[idx[i][s]] ----------------
// grid (1024, 8); coalesced dense bf16 row gathers, 2-way unrolled; no atomics.
template<bool OUTF32>
__global__ __launch_bounds__(256) void sp_chain(
    const float* __restrict__ wts,        // [B*N][CAP] compact weights
    const u16* __restrict__ rows,         // [B*N][1024] dense bf16 rows
    const u16* __restrict__ idxg, const int* __restrict__ cntg,
    u16* __restrict__ dstb, float* __restrict__ dstf)
{
  __shared__ u16 idxl[CAP];
  __shared__ float wl[CAP];
  const int b = blockIdx.y, i = blockIdx.x, tid = threadIdx.x;
  const int cnt = cntg[i];
  if (tid < CAP){
    idxl[tid] = idxg[(long)i*CAP + tid];
    wl[tid]   = wts[((long)(b*Nn + i))*CAP + tid];
  }
  __syncthreads();
  f32x4 acc = {0.f, 0.f, 0.f, 0.f};
  const int c0 = tid * 4;
  int s = 0;
  for (; s + 2 <= cnt; s += 2){
    int ja = idxl[s], jb = idxl[s+1];
    float ea = wl[s], eb = wl[s+1];
    u32x2 va = *(const u32x2*)(rows + ((long)(b*Nn + ja))*1024 + c0);
    u32x2 vb = *(const u32x2*)(rows + ((long)(b*Nn + jb))*1024 + c0);
    acc[0] += ea * bf2f((u16)(va[0] & 0xffff)) + eb * bf2f((u16)(vb[0] & 0xffff));
    acc[1] += ea * bf2f((u16)(va[0] >> 16))    + eb * bf2f((u16)(vb[0] >> 16));
    acc[2] += ea * bf2f((u16)(va[1] & 0xffff)) + eb * bf2f((u16)(vb[1] & 0xffff));
    acc[3] += ea * bf2f((u16)(va[1] >> 16))    + eb * bf2f((u16)(vb[1] >> 16));
  }
  if (s < cnt){
    int ja = idxl[s];
    float ea = wl[s];
    u32x2 va = *(const u32x2*)(rows + ((long)(b*Nn + ja))*1024 + c0);
    acc[0] += ea * bf2f((u16)(va[0] & 0xffff));
    acc[1] += ea * bf2f((u16)(va[0] >> 16));
    acc[2] += ea * bf2f((u16)(va[1] & 0xffff));
    acc[3] += ea * bf2f((u16)(va[1] >> 16));
  }
  if (OUTF32){
    *(f32x4*)(dstf + ((long)(b*Nn + i))*1024 + c0) = acc;
  } else {
    u32x2 pb;
    pb[0] = (u32)f2bf(acc[0]) | ((u32)f2bf(acc[1]) << 16);
    pb[1] = (u32)f2bf(acc[2]) | ((u32)f2bf(acc[3]) << 16);
    *(u32x2*)(dstb + ((long)(b*Nn + i))*1024 + c0) = pb;
  }
}

// ---------------- residual + layernorm ----------------
__global__ __launch_bounds__(256) void ln_kernel(
    const float* __restrict__ hin, const float* __restrict__ y,
    float* __restrict__ hout, u16* __restrict__ hb, float* __restrict__ outf,
    const float* __restrict__ g, const float* __restrict__ be)
{
  int row  = blockIdx.x * 4 + (threadIdx.x >> 6);
  int lane = threadIdx.x & 63;
  f32x4 v = *(const f32x4*)(hin + (long)row*Dd + lane*4)
          + *(const f32x4*)(y   + (long)row*Dd + lane*4);
  float s = v[0] + v[1] + v[2] + v[3];
  #pragma unroll
  for (int off = 32; off; off >>= 1) s += __shfl_xor(s, off, 64);
  float mu = s * (1.f/256.f);
  f32x4 d = v - mu;
  float q2 = d[0]*d[0] + d[1]*d[1] + d[2]*d[2] + d[3]*d[3];
  #pragma unroll
  for (int off = 32; off; off >>= 1) q2 += __shfl_xor(q2, off, 64);
  float rs = rsqrtf(q2 * (1.f/256.f) + 1e-5f);
  f32x4 ov;
  #pragma unroll
  for (int p = 0; p < 4; ++p)
    ov[p] = d[p] * rs * g[lane*4 + p] + be[lane*4 + p];
  *(f32x4*)(hout + (long)row*Dd + lane*4) = ov;
  if (hb){
    u32x2 pb;
    pb[0] = (u32)f2bf(ov[0]) | ((u32)f2bf(ov[1]) << 16);
    pb[1] = (u32)f2bf(ov[2]) | ((u32)f2bf(ov[3]) << 16);
    *(u32x2*)(hb + (long)row*Dd + lane*4) = pb;
  }
  if (outf)
    *(f32x4*)(outf + (long)row*Dd + lane*4) = ov;
}

extern "C" void kernel_launch(void* const* d_in, const int* in_sizes, int n_in,
                              void* d_out, int out_size, void* d_ws, size_t ws_size,
                              hipStream_t stream)
{
  (void)in_sizes; (void)n_in; (void)out_size; (void)ws_size;
  const float* x   = (const float*)d_in[0];
  const float* adj = (const float*)d_in[1];
  const float* W0  = (const float*)d_in[2];
  const float* Wq  = (const float*)d_in[3];
  const float* bq  = (const float*)d_in[4];
  const float* Wk  = (const float*)d_in[5];
  const float* bk  = (const float*)d_in[6];
  const float* Wv  = (const float*)d_in[7];
  const float* bv  = (const float*)d_in[8];
  const float* Wo  = (const float*)d_in[9];
  const float* bo  = (const float*)d_in[10];
  const float* gm  = (const float*)d_in[11];
  const float* bt  = (const float*)d_in[12];
  float* outf  = (float*)d_out;                 // f32 h region [8,1024,256]
  float* outat = outf + (long)Bb * Nn * Dd;     // f32 atten region [8,1024,1024]

  // ---- workspace (~83MB < proven 92MB) ----
  char* w = (char*)d_ws;
  u16* W0b  = (u16*)w; w += 131072;             // W0|Wq|Wk|Wv|Wo contiguous (conv_w5)
  u16* Wqb  = (u16*)w; w += 4*393216;
  float* bqkv = (float*)w; w += 9216;           // [3][768]
  u32* bitsg = (u32*)w; w += 131072;
  u16* idxg  = (u16*)w; w += 1024*CAP*2;        // 192KB
  int* cntg  = (int*)w; w += 4096;
  u16* xb  = (u16*)w; w += 4194304;
  u16* hb  = (u16*)w; w += 4194304;
  u16* qkv = (u16*)w; w += (long)Bb*Nn*768*2;   // 12MB
  u16* ob  = (u16*)w; w += 4194304;
  float* hbuf = (float*)w; w += 8388608;
  float* ybuf = (float*)w; w += 8388608;
  float* amv1 = (float*)w; w += (long)Bb*Nn*CAP*4;  // 3MB
  float* amv2 = (float*)w; w += (long)Bb*Nn*CAP*4;  // 3MB
  u16* P1   = (u16*)w; w += 16777216;           // [8][1024][1024] bf16
  u16* am0d = (u16*)w; w += 16777216;           // dense am0 [8][1024][1024] bf16

  dim3 blk(256);
  hipMemsetAsync(am0d, 0, (size_t)16777216, stream);
  f32_to_bf16<<<2048, blk, 0, stream>>>(x, xb, 2097152);
  conv_w5<<<833, blk, 0, stream>>>(W0, Wq, Wk, Wv, Wo, W0b, bq, bk, bv, bqkv);
  adj_to_bits<<<128, blk, 0, stream>>>(adj, bitsg);
  nbr_build<<<4, blk, 0, stream>>>(bitsg, idxg, cntg);

  // input projection: h = x @ W0^T  (f32 + bf16)
  gemm_bt<false,false,true,true><<<dim3(2,64,1), blk, 0, stream>>>(
      xb, 256, 0, W0b, 256, 0, hbuf, hb, 256, 0, 256, nullptr, 0, nullptr);

  for (int l = 0; l < 3; ++l){
    // fused q|k|v projection
    gemm_bt<true,false,false,true><<<dim3(2,64,3), blk, 0, stream>>>(
        hb, 256, 0, Wqb + (long)l*65536, 256, 196608,
        nullptr, qkv, 768, 256, 256, bqkv + l*768, 256, nullptr);
    // sparse attention: l0 writes dense am0d, l1/l2 write compact amv
    attn_sparse<<<dim3(256,8), blk, 0, stream>>>(
        qkv, ob, idxg, cntg,
        (l == 1 ? amv1 : amv2), am0d, (l == 0) ? 1 : 0);
    // y = o @ Wo^T + bo (f32)
    gemm_bt<true,false,true,false><<<dim3(2,64,1), blk, 0, stream>>>(
        ob, 256, 0, Wqb + (long)(3*3+l)*65536, 256, 0, ybuf, nullptr, 256, 0, 256,
        bo + l*256, 0, nullptr);
    // h = LN(h + y)
    ln_kernel<<<dim3(2048), blk, 0, stream>>>(
        hbuf, ybuf, hbuf, (l < 2 ? hb : nullptr), (l < 2 ? nullptr : outf),
        gm + l*256, bt + l*256);
    // chain: P1 = am1 @ am0d (bf16); final = am2 @ P1 (f32 -> d_out)
    if (l == 1)
      sp_chain<false><<<dim3(1024,8), blk, 0, stream>>>(
          amv1, am0d, idxg, cntg, P1, nullptr);
    if (l == 2)
      sp_chain<true><<<dim3(1024,8), blk, 0, stream>>>(
          amv2, P1, idxg, cntg, nullptr, outat);
  }
}